// Round 5
// baseline (3329.613 us; speedup 1.0000x reference)
//
#include <hip/hip_runtime.h>
#include <hip/hip_bf16.h>

#define B_ 8
#define T_ 2048
#define C_ 512
#define H_ 16
#define HS_ 32
#define BT_ (B_*T_)   // 16384 tokens

typedef __hip_bfloat16 bf16;

__device__ __forceinline__ float b2f(bf16 v) { return __bfloat162float(v); }
__device__ __forceinline__ bf16 f2b(float v) { return __float2bfloat16(v); }
__device__ __forceinline__ float us2f(unsigned short u) {
  union { unsigned int i; float f; } x; x.i = ((unsigned int)u) << 16; return x.f;
}
__device__ __forceinline__ float4 ld4bf(const bf16* p) {
  ushort4 u = *reinterpret_cast<const ushort4*>(p);
  return make_float4(us2f(u.x), us2f(u.y), us2f(u.z), us2f(u.w));
}

// ---------------------------------------------------------------------------
// K1: O = tanh(A' @ W). A':(BT,512). FUSE: A' = x + (xshift-x)*maa from fp32 x;
// else A' = A (bf16). W:(512,N) fp32 row-major. 16 rows/block.
// ---------------------------------------------------------------------------
template<int FUSE>
__global__ __launch_bounds__(256) void gemm_tanh_kernel(
    const bf16* __restrict__ A, const float* __restrict__ x,
    const float* __restrict__ maa, const float* __restrict__ W,
    bf16* __restrict__ O, int N) {
  __shared__ float As[16][C_];
  int row0 = blockIdx.x * 16;
  if (FUSE) {
    for (int e = threadIdx.x; e < 16 * C_; e += 256) {
      int rr = e >> 9, kk = e & (C_ - 1);
      int row = row0 + rr;
      int t = row & (T_ - 1);
      float xc = x[(size_t)row * C_ + kk];
      float xp = (t == 0) ? 0.f : x[(size_t)(row - 1) * C_ + kk];
      As[rr][kk] = xc + (xp - xc) * maa[kk];
    }
  } else {
    for (int e = threadIdx.x; e < 16 * C_; e += 256) {
      int rr = e >> 9, kk = e & (C_ - 1);
      As[rr][kk] = b2f(A[(size_t)(row0 + rr) * C_ + kk]);
    }
  }
  __syncthreads();
  int total = 16 * N;
  for (int o = threadIdx.x; o < total; o += 256) {
    int rr = o / N, n = o - rr * N;
    const float* wp = W + n;
    float acc = 0.f;
    #pragma unroll 8
    for (int k = 0; k < C_; ++k) acc += As[rr][k] * wp[k * N];
    O[(size_t)(row0 + rr) * N + n] = f2b(tanhf(acc));
  }
}

// ---------------------------------------------------------------------------
// K2: one mix pass: xf = x + xx*(tmf + m_f), m_f = mix5[:,f*32:(f+1)*32] @ w2[f]
// xx recomputed from fp32 x (token shift). 8 rows/block, 512 thr (1 chan each).
// ---------------------------------------------------------------------------
__global__ __launch_bounds__(512) void mixf_kernel(
    const bf16* __restrict__ mix5, const float* __restrict__ w2,
    const float* __restrict__ x, const float* __restrict__ tmf,
    bf16* __restrict__ xf, int f) {
  __shared__ float M[8][32];
  int row0 = blockIdx.x * 8;
  if (threadIdx.x < 256) {
    int rr = threadIdx.x >> 5, d = threadIdx.x & 31;
    M[rr][d] = b2f(mix5[(size_t)(row0 + rr) * 160 + f * 32 + d]);
  }
  __syncthreads();
  int c = threadIdx.x;
  float acc[8] = {0.f,0.f,0.f,0.f,0.f,0.f,0.f,0.f};
  for (int d = 0; d < 32; ++d) {
    float wv = w2[(size_t)(f * 32 + d) * C_ + c];
    #pragma unroll
    for (int r = 0; r < 8; ++r) acc[r] += M[r][d] * wv;
  }
  float tv = tmf[c];
  #pragma unroll
  for (int r = 0; r < 8; ++r) {
    int row = row0 + r;
    int t = row & (T_ - 1);
    size_t idx = (size_t)row * C_ + c;
    float xc = x[idx];
    float xp = (t == 0) ? 0.f : x[idx - C_];
    xf[idx] = f2b(xc + (xp - xc) * (tv + acc[r]));
  }
}

// ---------------------------------------------------------------------------
// K3: w = time_decay + h1 @ Wd2 (K=64); store e = exp(w) as bf16.
// (bf16 on exp(w): ~0.4% accumulated state error regardless of channel speed.)
// ---------------------------------------------------------------------------
__global__ __launch_bounds__(512) void decay_kernel(
    const bf16* __restrict__ h1, const float* __restrict__ wd2,
    const float* __restrict__ tdecay, bf16* __restrict__ ee) {
  __shared__ float Hs[8][64];
  int row0 = blockIdx.x * 8;
  {
    int e = threadIdx.x;
    Hs[e >> 6][e & 63] = b2f(h1[(size_t)(row0 + (e >> 6)) * 64 + (e & 63)]);
  }
  __syncthreads();
  int c = threadIdx.x;
  float acc[8] = {0.f,0.f,0.f,0.f,0.f,0.f,0.f,0.f};
  for (int j = 0; j < 64; ++j) {
    float wv = wd2[j * C_ + c];
    #pragma unroll
    for (int r = 0; r < 8; ++r) acc[r] += Hs[r][j] * wv;
  }
  float td = tdecay[c];
  #pragma unroll
  for (int r = 0; r < 8; ++r)
    ee[(size_t)(row0 + r) * C_ + c] = f2b(expf(td + acc[r]));
}

// ---------------------------------------------------------------------------
// K4: O = act(A @ B^T). A:(16384,512) bf16, B:(512,512) fp32 row-major (B is
// (out,in) so this is x@W.T). 64x64 tile, 256 thr, 4x4/thread.
// mode 0: bf16 out; mode 1: bf16 out + silu; mode 2: fp32 out (d_out!).
// ---------------------------------------------------------------------------
__global__ __launch_bounds__(256) void gemm_nt_kernel(
    const bf16* __restrict__ A, const float* __restrict__ Bm,
    void* __restrict__ O, int mode) {
  __shared__ float As[16][68];
  __shared__ float Bs[16][68];
  int m0 = blockIdx.x * 64, n0 = blockIdx.y * 64;
  int tid = threadIdx.x;
  int tx = tid & 15, ty = tid >> 4;
  float acc[4][4];
  #pragma unroll
  for (int i = 0; i < 4; ++i)
    #pragma unroll
    for (int j = 0; j < 4; ++j) acc[i][j] = 0.f;
  int rr = tid >> 2;
  int kg = (tid & 3) << 2;
  for (int k0 = 0; k0 < C_; k0 += 16) {
    float4 ua = ld4bf(&A[(size_t)(m0 + rr) * C_ + k0 + kg]);
    float4 ub = *reinterpret_cast<const float4*>(&Bm[(size_t)(n0 + rr) * C_ + k0 + kg]);
    __syncthreads();  // previous tile fully consumed
    As[kg + 0][rr] = ua.x; As[kg + 1][rr] = ua.y;
    As[kg + 2][rr] = ua.z; As[kg + 3][rr] = ua.w;
    Bs[kg + 0][rr] = ub.x; Bs[kg + 1][rr] = ub.y;
    Bs[kg + 2][rr] = ub.z; Bs[kg + 3][rr] = ub.w;
    __syncthreads();
    #pragma unroll
    for (int kk = 0; kk < 16; ++kk) {
      float4 av = *reinterpret_cast<const float4*>(&As[kk][ty << 2]);
      float4 bv = *reinterpret_cast<const float4*>(&Bs[kk][tx << 2]);
      acc[0][0] += av.x*bv.x; acc[0][1] += av.x*bv.y; acc[0][2] += av.x*bv.z; acc[0][3] += av.x*bv.w;
      acc[1][0] += av.y*bv.x; acc[1][1] += av.y*bv.y; acc[1][2] += av.y*bv.z; acc[1][3] += av.y*bv.w;
      acc[2][0] += av.z*bv.x; acc[2][1] += av.z*bv.y; acc[2][2] += av.z*bv.z; acc[2][3] += av.z*bv.w;
      acc[3][0] += av.w*bv.x; acc[3][1] += av.w*bv.y; acc[3][2] += av.w*bv.z; acc[3][3] += av.w*bv.w;
    }
  }
  #pragma unroll
  for (int i = 0; i < 4; ++i)
    #pragma unroll
    for (int j = 0; j < 4; ++j) {
      float vv = acc[i][j];
      if (mode == 1) vv = vv / (1.f + __expf(-vv));
      size_t oi = (size_t)(m0 + (ty << 2) + i) * C_ + n0 + (tx << 2) + j;
      if (mode == 2) ((float*)O)[oi] = vv;
      else           ((bf16*)O)[oi] = f2b(vv);
    }
}

// ---------------------------------------------------------------------------
// K5: WKV6 scan. One wave per (b,h). Lane l: i = l&31, half = l>>5 holds
// S[j][i] for j in half*16..+15.  y_i = sum_j r_j*S_ji + (sum_j r_j u_j k_j)*v_i
// S_ji <- d_j*S_ji + k_j*v_i  (y uses OLD S), d = exp(-e).  y stored bf16.
// ---------------------------------------------------------------------------
__global__ __launch_bounds__(64) void wkv_kernel(
    const bf16* __restrict__ r, const bf16* __restrict__ k,
    const bf16* __restrict__ v, const bf16* __restrict__ ee,
    const float* __restrict__ faaaa, bf16* __restrict__ y) {
  int bh = blockIdx.x;
  int b = bh >> 4, h = bh & 15;
  int lane = threadIdx.x;
  int i = lane & 31, half = lane >> 5;
  float S[16];
  #pragma unroll
  for (int jj = 0; jj < 16; ++jj) S[jj] = 0.f;
  float u_i = faaaa[h * HS_ + i];
  __shared__ float4 buf[2][32];
  size_t base = (size_t)b * T_ * C_ + h * HS_ + i;
  for (int t = 0; t < T_; ++t) {
    size_t idx = base + (size_t)t * C_;
    float rv  = b2f(r[idx]);
    float kv_ = b2f(k[idx]);
    float vv  = b2f(v[idx]);
    float dv  = expf(-b2f(ee[idx]));
    float aval = rv * u_i * kv_;
    aval += __shfl_xor(aval, 1);
    aval += __shfl_xor(aval, 2);
    aval += __shfl_xor(aval, 4);
    aval += __shfl_xor(aval, 8);
    aval += __shfl_xor(aval, 16);
    float4* cur = buf[t & 1];
    if (!half) cur[i] = make_float4(rv, kv_, dv, 0.f);
    __syncthreads();
    float p = 0.f;
    #pragma unroll
    for (int jj = 0; jj < 16; ++jj) {
      float4 q = cur[(half << 4) + jj];
      p += q.x * S[jj];                        // old S
      S[jj] = fmaf(q.z, S[jj], q.y * vv);      // decay + rank-1 update
    }
    p += __shfl_xor(p, 32);
    if (!half) y[idx] = f2b(p + aval * vv);
  }
}

// ---------------------------------------------------------------------------
// K6: per-(token,head) groupnorm over HS=32, * ln_w + ln_b, * silu(g) -> z bf16
// ---------------------------------------------------------------------------
__global__ __launch_bounds__(256) void gnorm_kernel(
    const bf16* __restrict__ y, const bf16* __restrict__ g,
    const float* __restrict__ lnw, const float* __restrict__ lnb,
    bf16* __restrict__ z) {
  int grp = blockIdx.x * 8 + (threadIdx.x >> 5);   // (token,head) group
  int i = threadIdx.x & 31;
  int token = grp >> 4, h = grp & 15;
  size_t idx = (size_t)token * C_ + h * HS_ + i;
  float yv = b2f(y[idx]);
  float mu = yv;
  mu += __shfl_xor(mu, 1); mu += __shfl_xor(mu, 2); mu += __shfl_xor(mu, 4);
  mu += __shfl_xor(mu, 8); mu += __shfl_xor(mu, 16);
  mu *= (1.f / 32.f);
  float d = yv - mu;
  float var = d * d;
  var += __shfl_xor(var, 1); var += __shfl_xor(var, 2); var += __shfl_xor(var, 4);
  var += __shfl_xor(var, 8); var += __shfl_xor(var, 16);
  var *= (1.f / 32.f);
  float yn = d * rsqrtf(var + 1e-5f);
  int c = h * HS_ + i;
  float outv = (yn * lnw[c] + lnb[c]) * b2f(g[idx]);  // g already silu'd
  z[idx] = f2b(outv);
}

// ---------------------------------------------------------------------------
extern "C" void kernel_launch(void* const* d_in, const int* in_sizes, int n_in,
                              void* d_out, int out_size, void* d_ws, size_t ws_size,
                              hipStream_t stream) {
  (void)in_sizes; (void)n_in; (void)out_size; (void)ws_size;
  const float* x      = (const float*)d_in[0];
  const float* tmx    = (const float*)d_in[1];
  const float* tmw    = (const float*)d_in[2];
  const float* tmk    = (const float*)d_in[3];
  const float* tmv    = (const float*)d_in[4];
  const float* tmr    = (const float*)d_in[5];
  const float* tmg    = (const float*)d_in[6];
  const float* w1     = (const float*)d_in[7];
  const float* w2     = (const float*)d_in[8];
  const float* tdecay = (const float*)d_in[9];
  const float* wd1    = (const float*)d_in[10];
  const float* wd2    = (const float*)d_in[11];
  const float* faaaa  = (const float*)d_in[12];
  const float* Wr     = (const float*)d_in[13];
  const float* Wk     = (const float*)d_in[14];
  const float* Wv     = (const float*)d_in[15];
  const float* Wg     = (const float*)d_in[16];
  const float* Wo     = (const float*)d_in[17];
  const float* lnw    = (const float*)d_in[18];
  const float* lnb    = (const float*)d_in[19];
  float* out = (float*)d_out;          // reference output dtype = float32

  // workspace layout — peak 87.25 MB (known-safe: ws >= 119 MB)
  char* w8 = (char*)d_ws;
  const size_t NE  = (size_t)BT_ * C_;          // 8,388,608 elements
  const size_t MB16 = NE * 2;                   // 16 MB per bf16 buffer
  bf16*  mixbuf = (bf16*)(w8);                  // [0,16) MB — staging, reused
  bf16*  rb     = (bf16*)(w8 + 1 * MB16);       // [16,32)
  bf16*  kb     = (bf16*)(w8 + 2 * MB16);       // [32,48)
  bf16*  vb     = (bf16*)(w8 + 3 * MB16);       // [48,64)
  bf16*  ee     = (bf16*)(w8 + 4 * MB16);       // [64,80)  e = exp(w), bf16
  bf16*  mix5   = (bf16*)(w8 + 5 * MB16);       // [80,85.25)
  bf16*  h1     = (bf16*)(w8 + 5 * MB16 + (size_t)BT_ * 160 * 2);  // [85.25,87.25)
  bf16*  yb     = mixbuf;   // reuse: mixbuf dead after v-gemm consumes xv
  bf16*  xgb    = kb;       // reuse: kb dead after wkv
  bf16*  gb     = vb;       // reuse: vb dead after wkv
  bf16*  zb     = rb;       // reuse: rb dead after wkv

  // mix5 = tanh((x + xx*maa_x) @ w1), token-shift fused
  gemm_tanh_kernel<1><<<BT_ / 16, 256, 0, stream>>>(nullptr, x, tmx, w1, mix5, 160);
  // w-pass: mixbuf = xw ; h1 = tanh(xw @ wd1) ; ee = exp(td + h1 @ wd2)
  mixf_kernel<<<BT_ / 8, 512, 0, stream>>>(mix5, w2, x, tmw, mixbuf, 0);
  gemm_tanh_kernel<0><<<BT_ / 16, 256, 0, stream>>>(mixbuf, nullptr, nullptr, wd1, h1, 64);
  decay_kernel<<<BT_ / 8, 512, 0, stream>>>(h1, wd2, tdecay, ee);
  dim3 gg(BT_ / 64, C_ / 64);
  // r-pass
  mixf_kernel<<<BT_ / 8, 512, 0, stream>>>(mix5, w2, x, tmr, mixbuf, 3);
  gemm_nt_kernel<<<gg, 256, 0, stream>>>(mixbuf, Wr, rb, 0);
  // k-pass
  mixf_kernel<<<BT_ / 8, 512, 0, stream>>>(mix5, w2, x, tmk, mixbuf, 1);
  gemm_nt_kernel<<<gg, 256, 0, stream>>>(mixbuf, Wk, kb, 0);
  // v-pass
  mixf_kernel<<<BT_ / 8, 512, 0, stream>>>(mix5, w2, x, tmv, mixbuf, 2);
  gemm_nt_kernel<<<gg, 256, 0, stream>>>(mixbuf, Wv, vb, 0);
  // scan (y -> mixbuf, free after v consumed)
  wkv_kernel<<<B_ * H_, 64, 0, stream>>>(rb, kb, vb, ee, faaaa, yb);
  // g-pass after scan: stage xg in kb (dead), g -> vb (dead), silu fused
  mixf_kernel<<<BT_ / 8, 512, 0, stream>>>(mix5, w2, x, tmg, xgb, 4);
  gemm_nt_kernel<<<gg, 256, 0, stream>>>(xgb, Wg, gb, 1);
  // groupnorm * g -> zb (= rb, dead), then output projection (fp32 out!)
  gnorm_kernel<<<(BT_ * H_) / 8, 256, 0, stream>>>(yb, gb, lnw, lnb, zb);
  gemm_nt_kernel<<<gg, 256, 0, stream>>>(zb, Wo, out, 2);
}

// Round 6
// 1478.410 us; speedup vs baseline: 2.2522x; 2.2522x over previous
//
#include <hip/hip_runtime.h>
#include <hip/hip_bf16.h>

#define B_ 8
#define T_ 2048
#define C_ 512
#define H_ 16
#define HS_ 32
#define BT_ (B_*T_)   // 16384 tokens
#define CL_ 64        // scan chunk length
#define NC_ (T_/CL_)  // 32 chunks
#define STF_ 1056     // floats per (bh,chunk) state: 1024 S + 32 P

typedef __hip_bfloat16 bf16;

__device__ __forceinline__ float b2f(bf16 v) { return __bfloat162float(v); }
__device__ __forceinline__ bf16 f2b(float v) { return __float2bfloat16(v); }
__device__ __forceinline__ float us2f(unsigned short u) {
  union { unsigned int i; float f; } x; x.i = ((unsigned int)u) << 16; return x.f;
}
__device__ __forceinline__ float4 ld4bf(const bf16* p) {
  ushort4 u = *reinterpret_cast<const ushort4*>(p);
  return make_float4(us2f(u.x), us2f(u.y), us2f(u.z), us2f(u.w));
}

// ---------------------------------------------------------------------------
// K1: O = tanh(A' @ W). A':(BT,512). FUSE: A' = x + (xshift-x)*maa from fp32 x;
// else A' = A (bf16). W:(512,N) fp32 row-major. 16 rows/block.
// ---------------------------------------------------------------------------
template<int FUSE>
__global__ __launch_bounds__(256) void gemm_tanh_kernel(
    const bf16* __restrict__ A, const float* __restrict__ x,
    const float* __restrict__ maa, const float* __restrict__ W,
    bf16* __restrict__ O, int N) {
  __shared__ float As[16][C_];
  int row0 = blockIdx.x * 16;
  if (FUSE) {
    for (int e = threadIdx.x; e < 16 * C_; e += 256) {
      int rr = e >> 9, kk = e & (C_ - 1);
      int row = row0 + rr;
      int t = row & (T_ - 1);
      float xc = x[(size_t)row * C_ + kk];
      float xp = (t == 0) ? 0.f : x[(size_t)(row - 1) * C_ + kk];
      As[rr][kk] = xc + (xp - xc) * maa[kk];
    }
  } else {
    for (int e = threadIdx.x; e < 16 * C_; e += 256) {
      int rr = e >> 9, kk = e & (C_ - 1);
      As[rr][kk] = b2f(A[(size_t)(row0 + rr) * C_ + kk]);
    }
  }
  __syncthreads();
  int total = 16 * N;
  for (int o = threadIdx.x; o < total; o += 256) {
    int rr = o / N, n = o - rr * N;
    const float* wp = W + n;
    float acc = 0.f;
    #pragma unroll 8
    for (int k = 0; k < C_; ++k) acc += As[rr][k] * wp[k * N];
    O[(size_t)(row0 + rr) * N + n] = f2b(tanhf(acc));
  }
}

// ---------------------------------------------------------------------------
// K2: one mix pass: xf = x + xx*(tmf + m_f), m_f = mix5[:,f*32:(f+1)*32] @ w2[f]
// ---------------------------------------------------------------------------
__global__ __launch_bounds__(512) void mixf_kernel(
    const bf16* __restrict__ mix5, const float* __restrict__ w2,
    const float* __restrict__ x, const float* __restrict__ tmf,
    bf16* __restrict__ xf, int f) {
  __shared__ float M[8][32];
  int row0 = blockIdx.x * 8;
  if (threadIdx.x < 256) {
    int rr = threadIdx.x >> 5, d = threadIdx.x & 31;
    M[rr][d] = b2f(mix5[(size_t)(row0 + rr) * 160 + f * 32 + d]);
  }
  __syncthreads();
  int c = threadIdx.x;
  float acc[8] = {0.f,0.f,0.f,0.f,0.f,0.f,0.f,0.f};
  for (int d = 0; d < 32; ++d) {
    float wv = w2[(size_t)(f * 32 + d) * C_ + c];
    #pragma unroll
    for (int r = 0; r < 8; ++r) acc[r] += M[r][d] * wv;
  }
  float tv = tmf[c];
  #pragma unroll
  for (int r = 0; r < 8; ++r) {
    int row = row0 + r;
    int t = row & (T_ - 1);
    size_t idx = (size_t)row * C_ + c;
    float xc = x[idx];
    float xp = (t == 0) ? 0.f : x[idx - C_];
    xf[idx] = f2b(xc + (xp - xc) * (tv + acc[r]));
  }
}

// ---------------------------------------------------------------------------
// K3: w = time_decay + h1 @ Wd2 (K=64); store e = exp(w) as bf16.
// ---------------------------------------------------------------------------
__global__ __launch_bounds__(512) void decay_kernel(
    const bf16* __restrict__ h1, const float* __restrict__ wd2,
    const float* __restrict__ tdecay, bf16* __restrict__ ee) {
  __shared__ float Hs[8][64];
  int row0 = blockIdx.x * 8;
  {
    int e = threadIdx.x;
    Hs[e >> 6][e & 63] = b2f(h1[(size_t)(row0 + (e >> 6)) * 64 + (e & 63)]);
  }
  __syncthreads();
  int c = threadIdx.x;
  float acc[8] = {0.f,0.f,0.f,0.f,0.f,0.f,0.f,0.f};
  for (int j = 0; j < 64; ++j) {
    float wv = wd2[j * C_ + c];
    #pragma unroll
    for (int r = 0; r < 8; ++r) acc[r] += Hs[r][j] * wv;
  }
  float td = tdecay[c];
  #pragma unroll
  for (int r = 0; r < 8; ++r)
    ee[(size_t)(row0 + r) * C_ + c] = f2b(expf(td + acc[r]));
}

// ---------------------------------------------------------------------------
// K4: O = act(A @ B^T). 64x64 tile, 256 thr, 4x4/thread.
// mode 0: bf16 out; 1: bf16 + silu; 2: fp32 out (d_out).
// ---------------------------------------------------------------------------
__global__ __launch_bounds__(256) void gemm_nt_kernel(
    const bf16* __restrict__ A, const float* __restrict__ Bm,
    void* __restrict__ O, int mode) {
  __shared__ float As[16][68];
  __shared__ float Bs[16][68];
  int m0 = blockIdx.x * 64, n0 = blockIdx.y * 64;
  int tid = threadIdx.x;
  int tx = tid & 15, ty = tid >> 4;
  float acc[4][4];
  #pragma unroll
  for (int i = 0; i < 4; ++i)
    #pragma unroll
    for (int j = 0; j < 4; ++j) acc[i][j] = 0.f;
  int rr = tid >> 2;
  int kg = (tid & 3) << 2;
  for (int k0 = 0; k0 < C_; k0 += 16) {
    float4 ua = ld4bf(&A[(size_t)(m0 + rr) * C_ + k0 + kg]);
    float4 ub = *reinterpret_cast<const float4*>(&Bm[(size_t)(n0 + rr) * C_ + k0 + kg]);
    __syncthreads();
    As[kg + 0][rr] = ua.x; As[kg + 1][rr] = ua.y;
    As[kg + 2][rr] = ua.z; As[kg + 3][rr] = ua.w;
    Bs[kg + 0][rr] = ub.x; Bs[kg + 1][rr] = ub.y;
    Bs[kg + 2][rr] = ub.z; Bs[kg + 3][rr] = ub.w;
    __syncthreads();
    #pragma unroll
    for (int kk = 0; kk < 16; ++kk) {
      float4 av = *reinterpret_cast<const float4*>(&As[kk][ty << 2]);
      float4 bv = *reinterpret_cast<const float4*>(&Bs[kk][tx << 2]);
      acc[0][0] += av.x*bv.x; acc[0][1] += av.x*bv.y; acc[0][2] += av.x*bv.z; acc[0][3] += av.x*bv.w;
      acc[1][0] += av.y*bv.x; acc[1][1] += av.y*bv.y; acc[1][2] += av.y*bv.z; acc[1][3] += av.y*bv.w;
      acc[2][0] += av.z*bv.x; acc[2][1] += av.z*bv.y; acc[2][2] += av.z*bv.z; acc[2][3] += av.z*bv.w;
      acc[3][0] += av.w*bv.x; acc[3][1] += av.w*bv.y; acc[3][2] += av.w*bv.z; acc[3][3] += av.w*bv.w;
    }
  }
  #pragma unroll
  for (int i = 0; i < 4; ++i)
    #pragma unroll
    for (int j = 0; j < 4; ++j) {
      float vv = acc[i][j];
      if (mode == 1) vv = vv / (1.f + __expf(-vv));
      size_t oi = (size_t)(m0 + (ty << 2) + i) * C_ + n0 + (tx << 2) + j;
      if (mode == 2) ((float*)O)[oi] = vv;
      else           ((bf16*)O)[oi] = f2b(vv);
    }
}

// ---------------------------------------------------------------------------
// WKV6 chunked scan.  State layout per (bh,c) in st: S[i][j] at i*32+j
// (i = output chan, j = decayed chan), P[j] at 1024+j.  Lane (i=l&31,
// half=l>>5) holds S[j=half*16+jj][i], i.e. 16 contiguous floats at
// st[i*32 + half*16].
// ---------------------------------------------------------------------------
// Pass 1: per-chunk suffix state Sc and decay product P (no y, no r).
__global__ __launch_bounds__(64) void wkv_partial_kernel(
    const bf16* __restrict__ k, const bf16* __restrict__ v,
    const bf16* __restrict__ ee, float* __restrict__ st) {
  int g = blockIdx.x;                // bh*NC_ + c
  int bh = g >> 5, c = g & (NC_ - 1);
  int b = bh >> 4, h = bh & 15;
  int lane = threadIdx.x;
  int i = lane & 31, half = lane >> 5;
  float S[16];
  #pragma unroll
  for (int jj = 0; jj < 16; ++jj) S[jj] = 0.f;
  float P = 1.f;
  __shared__ float2 buf[2][32];
  size_t base = (size_t)b * T_ * C_ + (size_t)(c * CL_) * C_ + h * HS_ + i;
  for (int t = 0; t < CL_; ++t) {
    size_t idx = base + (size_t)t * C_;
    float kv_ = b2f(k[idx]);
    float vv  = b2f(v[idx]);
    float dv  = expf(-b2f(ee[idx]));
    float2* cur = buf[t & 1];
    if (!half) cur[i] = make_float2(kv_, dv);
    __syncthreads();
    #pragma unroll
    for (int jj = 0; jj < 16; ++jj) {
      float2 q = cur[(half << 4) + jj];
      S[jj] = fmaf(q.y, S[jj], q.x * vv);
    }
    P *= dv;
  }
  float* sp = st + (size_t)g * STF_ + i * 32 + (half << 4);
  float4* s4 = reinterpret_cast<float4*>(S);
  float4* sp4 = reinterpret_cast<float4*>(sp);
  #pragma unroll
  for (int q = 0; q < 4; ++q) sp4[q] = s4[q];
  if (!half) st[(size_t)g * STF_ + 1024 + i] = P;   // lanes 0..31 cover all j
}

// Pass 2: stitch — sequentially combine chunk states; overwrite slot c with
// the INITIAL state for chunk c.  R(0)=0; R(c+1) = P(c) (x) R(c) + Sc(c).
__global__ __launch_bounds__(64) void wkv_stitch_kernel(float* __restrict__ st) {
  int bh = blockIdx.x;
  int lane = threadIdx.x;
  int i = lane & 31, half = lane >> 5;
  float R[16];
  #pragma unroll
  for (int jj = 0; jj < 16; ++jj) R[jj] = 0.f;
  for (int c = 0; c < NC_; ++c) {
    size_t s = ((size_t)bh * NC_ + c) * STF_;
    float* sp = st + s + i * 32 + (half << 4);
    float Sc[16];
    float4* sc4 = reinterpret_cast<float4*>(Sc);
    float4* sp4 = reinterpret_cast<float4*>(sp);
    #pragma unroll
    for (int q = 0; q < 4; ++q) sc4[q] = sp4[q];
    float Pj[16];
    #pragma unroll
    for (int jj = 0; jj < 16; ++jj) Pj[jj] = st[s + 1024 + (half << 4) + jj];
    // overwrite slot with initial state R, then advance
    float4* r4 = reinterpret_cast<float4*>(R);
    #pragma unroll
    for (int q = 0; q < 4; ++q) sp4[q] = r4[q];
    #pragma unroll
    for (int jj = 0; jj < 16; ++jj) R[jj] = fmaf(Pj[jj], R[jj], Sc[jj]);
  }
}

// Pass 3: re-run chunk scan from S_init with u-bonus, emit y (bf16).
__global__ __launch_bounds__(64) void wkv_final_kernel(
    const bf16* __restrict__ r, const bf16* __restrict__ k,
    const bf16* __restrict__ v, const bf16* __restrict__ ee,
    const float* __restrict__ faaaa, const float* __restrict__ st,
    bf16* __restrict__ y) {
  int g = blockIdx.x;
  int bh = g >> 5, c = g & (NC_ - 1);
  int b = bh >> 4, h = bh & 15;
  int lane = threadIdx.x;
  int i = lane & 31, half = lane >> 5;
  float S[16];
  {
    const float* sp = st + (size_t)g * STF_ + i * 32 + (half << 4);
    const float4* sp4 = reinterpret_cast<const float4*>(sp);
    float4* s4 = reinterpret_cast<float4*>(S);
    #pragma unroll
    for (int q = 0; q < 4; ++q) s4[q] = sp4[q];
  }
  float u_i = faaaa[h * HS_ + i];
  __shared__ float4 buf[2][32];
  size_t base = (size_t)b * T_ * C_ + (size_t)(c * CL_) * C_ + h * HS_ + i;
  for (int t = 0; t < CL_; ++t) {
    size_t idx = base + (size_t)t * C_;
    float rv  = b2f(r[idx]);
    float kv_ = b2f(k[idx]);
    float vv  = b2f(v[idx]);
    float dv  = expf(-b2f(ee[idx]));
    float aval = rv * u_i * kv_;
    aval += __shfl_xor(aval, 1);
    aval += __shfl_xor(aval, 2);
    aval += __shfl_xor(aval, 4);
    aval += __shfl_xor(aval, 8);
    aval += __shfl_xor(aval, 16);
    float4* cur = buf[t & 1];
    if (!half) cur[i] = make_float4(rv, kv_, dv, 0.f);
    __syncthreads();
    float p = 0.f;
    #pragma unroll
    for (int jj = 0; jj < 16; ++jj) {
      float4 q = cur[(half << 4) + jj];
      p += q.x * S[jj];                        // old S
      S[jj] = fmaf(q.z, S[jj], q.y * vv);      // decay + rank-1 update
    }
    p += __shfl_xor(p, 32);
    if (!half) y[idx] = f2b(p + aval * vv);
  }
}

// ---------------------------------------------------------------------------
// K6: per-(token,head) groupnorm over HS=32, * ln_w + ln_b, * silu(g) -> z bf16
// ---------------------------------------------------------------------------
__global__ __launch_bounds__(256) void gnorm_kernel(
    const bf16* __restrict__ y, const bf16* __restrict__ g,
    const float* __restrict__ lnw, const float* __restrict__ lnb,
    bf16* __restrict__ z) {
  int grp = blockIdx.x * 8 + (threadIdx.x >> 5);
  int i = threadIdx.x & 31;
  int token = grp >> 4, h = grp & 15;
  size_t idx = (size_t)token * C_ + h * HS_ + i;
  float yv = b2f(y[idx]);
  float mu = yv;
  mu += __shfl_xor(mu, 1); mu += __shfl_xor(mu, 2); mu += __shfl_xor(mu, 4);
  mu += __shfl_xor(mu, 8); mu += __shfl_xor(mu, 16);
  mu *= (1.f / 32.f);
  float d = yv - mu;
  float var = d * d;
  var += __shfl_xor(var, 1); var += __shfl_xor(var, 2); var += __shfl_xor(var, 4);
  var += __shfl_xor(var, 8); var += __shfl_xor(var, 16);
  var *= (1.f / 32.f);
  float yn = d * rsqrtf(var + 1e-5f);
  int c = h * HS_ + i;
  float outv = (yn * lnw[c] + lnb[c]) * b2f(g[idx]);
  z[idx] = f2b(outv);
}

// ---------------------------------------------------------------------------
extern "C" void kernel_launch(void* const* d_in, const int* in_sizes, int n_in,
                              void* d_out, int out_size, void* d_ws, size_t ws_size,
                              hipStream_t stream) {
  (void)in_sizes; (void)n_in; (void)out_size; (void)ws_size;
  const float* x      = (const float*)d_in[0];
  const float* tmx    = (const float*)d_in[1];
  const float* tmw    = (const float*)d_in[2];
  const float* tmk    = (const float*)d_in[3];
  const float* tmv    = (const float*)d_in[4];
  const float* tmr    = (const float*)d_in[5];
  const float* tmg    = (const float*)d_in[6];
  const float* w1     = (const float*)d_in[7];
  const float* w2     = (const float*)d_in[8];
  const float* tdecay = (const float*)d_in[9];
  const float* wd1    = (const float*)d_in[10];
  const float* wd2    = (const float*)d_in[11];
  const float* faaaa  = (const float*)d_in[12];
  const float* Wr     = (const float*)d_in[13];
  const float* Wk     = (const float*)d_in[14];
  const float* Wv     = (const float*)d_in[15];
  const float* Wg     = (const float*)d_in[16];
  const float* Wo     = (const float*)d_in[17];
  const float* lnw    = (const float*)d_in[18];
  const float* lnb    = (const float*)d_in[19];
  float* out = (float*)d_out;          // reference output dtype = float32

  // workspace layout — peak ~105 MB (ws known-safe >= 119 MB)
  char* w8 = (char*)d_ws;
  const size_t NE  = (size_t)BT_ * C_;
  const size_t MB16 = NE * 2;
  bf16*  mixbuf = (bf16*)(w8);                  // [0,16) MB — staging, reused
  bf16*  rb     = (bf16*)(w8 + 1 * MB16);
  bf16*  kb     = (bf16*)(w8 + 2 * MB16);
  bf16*  vb     = (bf16*)(w8 + 3 * MB16);
  bf16*  ee     = (bf16*)(w8 + 4 * MB16);       // e = exp(w), bf16
  bf16*  mix5   = (bf16*)(w8 + 5 * MB16);
  bf16*  h1     = (bf16*)(w8 + 5 * MB16 + (size_t)BT_ * 160 * 2);
  float* st     = (float*)(w8 + 88 * 1024 * 1024);  // chunk states, 16.5 MB
  bf16*  yb     = mixbuf;   // reuse
  bf16*  xgb    = kb;       // reuse after wkv
  bf16*  gb     = vb;       // reuse after wkv
  bf16*  zb     = rb;       // reuse after wkv

  gemm_tanh_kernel<1><<<BT_ / 16, 256, 0, stream>>>(nullptr, x, tmx, w1, mix5, 160);
  mixf_kernel<<<BT_ / 8, 512, 0, stream>>>(mix5, w2, x, tmw, mixbuf, 0);
  gemm_tanh_kernel<0><<<BT_ / 16, 256, 0, stream>>>(mixbuf, nullptr, nullptr, wd1, h1, 64);
  decay_kernel<<<BT_ / 8, 512, 0, stream>>>(h1, wd2, tdecay, ee);
  dim3 gg(BT_ / 64, C_ / 64);
  mixf_kernel<<<BT_ / 8, 512, 0, stream>>>(mix5, w2, x, tmr, mixbuf, 3);
  gemm_nt_kernel<<<gg, 256, 0, stream>>>(mixbuf, Wr, rb, 0);
  mixf_kernel<<<BT_ / 8, 512, 0, stream>>>(mix5, w2, x, tmk, mixbuf, 1);
  gemm_nt_kernel<<<gg, 256, 0, stream>>>(mixbuf, Wk, kb, 0);
  mixf_kernel<<<BT_ / 8, 512, 0, stream>>>(mix5, w2, x, tmv, mixbuf, 2);
  gemm_nt_kernel<<<gg, 256, 0, stream>>>(mixbuf, Wv, vb, 0);
  // chunk-parallel WKV6 scan
  wkv_partial_kernel<<<B_ * H_ * NC_, 64, 0, stream>>>(kb, vb, ee, st);
  wkv_stitch_kernel<<<B_ * H_, 64, 0, stream>>>(st);
  wkv_final_kernel<<<B_ * H_ * NC_, 64, 0, stream>>>(rb, kb, vb, ee, faaaa, st, yb);
  // g-pass after scan (buffers freed), silu fused
  mixf_kernel<<<BT_ / 8, 512, 0, stream>>>(mix5, w2, x, tmg, xgb, 4);
  gemm_nt_kernel<<<gg, 256, 0, stream>>>(xgb, Wg, gb, 1);
  gnorm_kernel<<<(BT_ * H_) / 8, 256, 0, stream>>>(yb, gb, lnw, lnb, zb);
  gemm_nt_kernel<<<gg, 256, 0, stream>>>(zb, Wo, out, 2);
}

// Round 8
// 859.869 us; speedup vs baseline: 3.8722x; 1.7193x over previous
//
#include <hip/hip_runtime.h>
#include <hip/hip_bf16.h>

#define B_ 8
#define T_ 2048
#define C_ 512
#define H_ 16
#define HS_ 32
#define BT_ (B_*T_)   // 16384 tokens
#define CL_ 64        // scan chunk length
#define NC_ (T_/CL_)  // 32 chunks
#define STF_ 1056     // floats per (bh,chunk) state: 1024 S + 32 P
#define WSZ_ 262144   // elements per 512x512 weight

typedef __hip_bfloat16 bf16;
typedef __attribute__((ext_vector_type(8))) short short8;
typedef __attribute__((ext_vector_type(4))) float f32x4;

__device__ __forceinline__ float b2f(bf16 v) { return __bfloat162float(v); }
__device__ __forceinline__ bf16 f2b(float v) { return __float2bfloat16(v); }

// ---------------------------------------------------------------------------
// Weight prep. split: W -> hi bf16 + lo bf16 (lo = round(W - hi)); the pair
// reproduces fp32 weights to ~2^-17 relative — removes the round-7 regression.
// ---------------------------------------------------------------------------
__global__ __launch_bounds__(256) void conv_split_kernel(
    const float* __restrict__ src, bf16* __restrict__ dst, int n) {
  int i = blockIdx.x * 256 + threadIdx.x;
  if (i < n) {
    float s = src[i];
    bf16 hi = f2b(s);
    dst[i] = hi;
    dst[n + i] = f2b(s - b2f(hi));
  }
}
// src fp32 [C_][nsrc]  ->  dst bf16 [npad][C_], rows >= nsrc zero-filled
__global__ __launch_bounds__(256) void conv_t_kernel(
    const float* __restrict__ src, bf16* __restrict__ dst, int nsrc) {
  int i = blockIdx.x * 256 + threadIdx.x;   // over npad*C_
  int n = i >> 9, k = i & (C_ - 1);
  dst[i] = f2b(n < nsrc ? src[k * nsrc + n] : 0.f);
}

// ---------------------------------------------------------------------------
// prep: xxx = x + (xshift - x)*maa_x   (bf16 out)
// ---------------------------------------------------------------------------
__global__ __launch_bounds__(256) void prep_kernel(
    const float* __restrict__ x, const float* __restrict__ tmx,
    bf16* __restrict__ xxx) {
  int idx = blockIdx.x * 256 + threadIdx.x;
  int c = idx & (C_ - 1);
  int t = (idx >> 9) & (T_ - 1);
  float xc = x[idx];
  float xp = (t == 0) ? 0.f : x[idx - C_];
  xxx[idx] = f2b(xc + (xp - xc) * tmx[c]);
}

// ---------------------------------------------------------------------------
// MFMA GEMM: O = act(A @ Bw^T). A:[M][512] bf16, Bw:[n][512] bf16 (+ lo copy
// at Bw+WSZ_ when SPLIT). BM=128, BK=32, 256 thr (4 waves). LDS in fragment
// order: element e = g*64 + quad*16 + m at byte e*16 -> ds_read_b128
// conflict-free, feeds v_mfma_f32_16x16x32_bf16 (A: m=lane&15,k=quad*8+j;
// C/D: col=lane&15,row=quad*4+reg — m89/m91-verified).
// MODE: 0 bf16; 1 bf16+silu; 2 fp32; 3 bf16+tanh.  N = output stride.
// ---------------------------------------------------------------------------
template<int BN, int MODE, int SPLIT>
__global__ __launch_bounds__(256) void mfma_gemm_kernel(
    const bf16* __restrict__ A, const bf16* __restrict__ Bw,
    void* __restrict__ O, int N) {
  constexpr int BM = 128, BK = 32;
  constexpr int AE = BM * BK / 8;           // 512 LDS entries of 16B
  constexpr int BE = BN * BK / 8;           // 512 or 256
  __shared__ short8 Asm[AE];
  __shared__ short8 Bsm[BE];
  __shared__ short8 Lsm[SPLIT ? BE : 1];
  const int tid = threadIdx.x;
  const int lane = tid & 63;
  const int wave = tid >> 6;
  const int m0 = blockIdx.x * BM;
  const int n0 = blockIdx.y * BN;
  const int wm = (BN == 128) ? (wave >> 1) * 64 : wave * 32;
  const int wn = (BN == 128) ? (wave & 1) * 64 : 0;
  constexpr int MT = (BN == 128) ? 4 : 2;
  constexpr int NT = 4;
  f32x4 acc[MT][NT] = {};
  const int e0 = tid, e1 = tid + 256;
  const int r0 = ((e0 >> 6) << 4) | (e0 & 15), q0 = (e0 >> 4) & 3;
  const int r1 = ((e1 >> 6) << 4) | (e1 & 15), q1 = (e1 >> 4) & 3;
  const unsigned short* Au = (const unsigned short*)A;
  const unsigned short* Bu = (const unsigned short*)Bw;
  const unsigned short* Lu = Bu + (SPLIT ? WSZ_ : 0);
  for (int k0 = 0; k0 < C_; k0 += BK) {
    short8 a0 = *(const short8*)&Au[(size_t)(m0 + r0) * C_ + k0 + q0 * 8];
    short8 a1 = *(const short8*)&Au[(size_t)(m0 + r1) * C_ + k0 + q1 * 8];
    short8 b0 = *(const short8*)&Bu[(size_t)(n0 + r0) * C_ + k0 + q0 * 8];
    short8 b1, l0, l1;
    if constexpr (BN == 128)
      b1 = *(const short8*)&Bu[(size_t)(n0 + r1) * C_ + k0 + q1 * 8];
    if constexpr (SPLIT) {
      l0 = *(const short8*)&Lu[(size_t)(n0 + r0) * C_ + k0 + q0 * 8];
      if constexpr (BN == 128)
        l1 = *(const short8*)&Lu[(size_t)(n0 + r1) * C_ + k0 + q1 * 8];
    }
    __syncthreads();                     // previous tile fully consumed
    Asm[e0] = a0; Asm[e1] = a1;
    Bsm[e0] = b0;
    if constexpr (BN == 128) Bsm[e1] = b1;
    if constexpr (SPLIT) {
      Lsm[e0] = l0;
      if constexpr (BN == 128) Lsm[e1] = l1;
    }
    __syncthreads();                     // staging visible
    short8 af[MT], bh[NT];
    #pragma unroll
    for (int mt = 0; mt < MT; ++mt) af[mt] = Asm[((wm >> 4) + mt) * 64 + lane];
    #pragma unroll
    for (int nt = 0; nt < NT; ++nt) bh[nt] = Bsm[((wn >> 4) + nt) * 64 + lane];
    #pragma unroll
    for (int mt = 0; mt < MT; ++mt)
      #pragma unroll
      for (int nt = 0; nt < NT; ++nt)
        acc[mt][nt] = __builtin_amdgcn_mfma_f32_16x16x32_bf16(
            af[mt], bh[nt], acc[mt][nt], 0, 0, 0);
    if constexpr (SPLIT) {
      short8 bl[NT];
      #pragma unroll
      for (int nt = 0; nt < NT; ++nt) bl[nt] = Lsm[((wn >> 4) + nt) * 64 + lane];
      #pragma unroll
      for (int mt = 0; mt < MT; ++mt)
        #pragma unroll
        for (int nt = 0; nt < NT; ++nt)
          acc[mt][nt] = __builtin_amdgcn_mfma_f32_16x16x32_bf16(
              af[mt], bl[nt], acc[mt][nt], 0, 0, 0);
    }
  }
  const int col = lane & 15, qr = lane >> 4;
  #pragma unroll
  for (int mt = 0; mt < MT; ++mt) {
    int mrow = m0 + wm + mt * 16 + qr * 4;
    #pragma unroll
    for (int nt = 0; nt < NT; ++nt) {
      int nc = n0 + wn + nt * 16 + col;
      #pragma unroll
      for (int r = 0; r < 4; ++r) {
        float v = acc[mt][nt][r];
        if (MODE == 1) v = v / (1.f + __expf(-v));
        if (MODE == 3) v = tanhf(v);
        size_t oi = (size_t)(mrow + r) * N + nc;
        if (MODE == 2) ((float*)O)[oi] = v;
        else           ((bf16*)O)[oi] = f2b(v);
      }
    }
  }
}

// ---------------------------------------------------------------------------
// mix pass: xf = x + xx*(tmf + m_f), m_f = mix5p[:, f*32:(f+1)*32] @ w2[f]
// mix5p row stride 192 (padded). 8 rows/block, 512 thr.
// ---------------------------------------------------------------------------
__global__ __launch_bounds__(512) void mixf_kernel(
    const bf16* __restrict__ mix5, const float* __restrict__ w2,
    const float* __restrict__ x, const float* __restrict__ tmf,
    bf16* __restrict__ xf, int f) {
  __shared__ float M[8][32];
  int row0 = blockIdx.x * 8;
  if (threadIdx.x < 256) {
    int rr = threadIdx.x >> 5, d = threadIdx.x & 31;
    M[rr][d] = b2f(mix5[(size_t)(row0 + rr) * 192 + f * 32 + d]);
  }
  __syncthreads();
  int c = threadIdx.x;
  float acc[8] = {0.f,0.f,0.f,0.f,0.f,0.f,0.f,0.f};
  for (int d = 0; d < 32; ++d) {
    float wv = w2[(size_t)(f * 32 + d) * C_ + c];
    #pragma unroll
    for (int r = 0; r < 8; ++r) acc[r] += M[r][d] * wv;
  }
  float tv = tmf[c];
  #pragma unroll
  for (int r = 0; r < 8; ++r) {
    int row = row0 + r;
    int t = row & (T_ - 1);
    size_t idx = (size_t)row * C_ + c;
    float xc = x[idx];
    float xp = (t == 0) ? 0.f : x[idx - C_];
    xf[idx] = f2b(xc + (xp - xc) * (tv + acc[r]));
  }
}

// ---------------------------------------------------------------------------
// decay: w = time_decay + h1 @ Wd2 (K=64); store e = exp(w) as bf16.
// ---------------------------------------------------------------------------
__global__ __launch_bounds__(512) void decay_kernel(
    const bf16* __restrict__ h1, const float* __restrict__ wd2,
    const float* __restrict__ tdecay, bf16* __restrict__ ee) {
  __shared__ float Hs[8][64];
  int row0 = blockIdx.x * 8;
  {
    int e = threadIdx.x;
    Hs[e >> 6][e & 63] = b2f(h1[(size_t)(row0 + (e >> 6)) * 64 + (e & 63)]);
  }
  __syncthreads();
  int c = threadIdx.x;
  float acc[8] = {0.f,0.f,0.f,0.f,0.f,0.f,0.f,0.f};
  for (int j = 0; j < 64; ++j) {
    float wv = wd2[j * C_ + c];
    #pragma unroll
    for (int r = 0; r < 8; ++r) acc[r] += Hs[r][j] * wv;
  }
  float td = tdecay[c];
  #pragma unroll
  for (int r = 0; r < 8; ++r)
    ee[(size_t)(row0 + r) * C_ + c] = f2b(expf(td + acc[r]));
}

// ---------------------------------------------------------------------------
// WKV6 chunked scan (verified in round 6).
// ---------------------------------------------------------------------------
__global__ __launch_bounds__(64) void wkv_partial_kernel(
    const bf16* __restrict__ k, const bf16* __restrict__ v,
    const bf16* __restrict__ ee, float* __restrict__ st) {
  int g = blockIdx.x;                // bh*NC_ + c
  int bh = g >> 5, c = g & (NC_ - 1);
  int b = bh >> 4, h = bh & 15;
  int lane = threadIdx.x;
  int i = lane & 31, half = lane >> 5;
  float S[16];
  #pragma unroll
  for (int jj = 0; jj < 16; ++jj) S[jj] = 0.f;
  float P = 1.f;
  __shared__ float2 buf[2][32];
  size_t base = (size_t)b * T_ * C_ + (size_t)(c * CL_) * C_ + h * HS_ + i;
  for (int t = 0; t < CL_; ++t) {
    size_t idx = base + (size_t)t * C_;
    float kv_ = b2f(k[idx]);
    float vv  = b2f(v[idx]);
    float dv  = expf(-b2f(ee[idx]));
    float2* cur = buf[t & 1];
    if (!half) cur[i] = make_float2(kv_, dv);
    __syncthreads();
    #pragma unroll
    for (int jj = 0; jj < 16; ++jj) {
      float2 q = cur[(half << 4) + jj];
      S[jj] = fmaf(q.y, S[jj], q.x * vv);
    }
    P *= dv;
  }
  float* sp = st + (size_t)g * STF_ + i * 32 + (half << 4);
  float4* s4 = reinterpret_cast<float4*>(S);
  float4* sp4 = reinterpret_cast<float4*>(sp);
  #pragma unroll
  for (int q = 0; q < 4; ++q) sp4[q] = s4[q];
  if (!half) st[(size_t)g * STF_ + 1024 + i] = P;
}

__global__ __launch_bounds__(64) void wkv_stitch_kernel(float* __restrict__ st) {
  int bh = blockIdx.x;
  int lane = threadIdx.x;
  int i = lane & 31, half = lane >> 5;
  float R[16];
  #pragma unroll
  for (int jj = 0; jj < 16; ++jj) R[jj] = 0.f;
  for (int c = 0; c < NC_; ++c) {
    size_t s = ((size_t)bh * NC_ + c) * STF_;
    float* sp = st + s + i * 32 + (half << 4);
    float Sc[16];
    float4* sc4 = reinterpret_cast<float4*>(Sc);
    float4* sp4 = reinterpret_cast<float4*>(sp);
    #pragma unroll
    for (int q = 0; q < 4; ++q) sc4[q] = sp4[q];
    float Pj[16];
    #pragma unroll
    for (int jj = 0; jj < 16; ++jj) Pj[jj] = st[s + 1024 + (half << 4) + jj];
    float4* r4 = reinterpret_cast<float4*>(R);
    #pragma unroll
    for (int q = 0; q < 4; ++q) sp4[q] = r4[q];
    #pragma unroll
    for (int jj = 0; jj < 16; ++jj) R[jj] = fmaf(Pj[jj], R[jj], Sc[jj]);
  }
}

__global__ __launch_bounds__(64) void wkv_final_kernel(
    const bf16* __restrict__ r, const bf16* __restrict__ k,
    const bf16* __restrict__ v, const bf16* __restrict__ ee,
    const float* __restrict__ faaaa, const float* __restrict__ st,
    bf16* __restrict__ y) {
  int g = blockIdx.x;
  int bh = g >> 5, c = g & (NC_ - 1);
  int b = bh >> 4, h = bh & 15;
  int lane = threadIdx.x;
  int i = lane & 31, half = lane >> 5;
  float S[16];
  {
    const float* sp = st + (size_t)g * STF_ + i * 32 + (half << 4);
    const float4* sp4 = reinterpret_cast<const float4*>(sp);
    float4* s4 = reinterpret_cast<float4*>(S);
    #pragma unroll
    for (int q = 0; q < 4; ++q) s4[q] = sp4[q];
  }
  float u_i = faaaa[h * HS_ + i];
  __shared__ float4 buf[2][32];
  size_t base = (size_t)b * T_ * C_ + (size_t)(c * CL_) * C_ + h * HS_ + i;
  for (int t = 0; t < CL_; ++t) {
    size_t idx = base + (size_t)t * C_;
    float rv  = b2f(r[idx]);
    float kv_ = b2f(k[idx]);
    float vv  = b2f(v[idx]);
    float dv  = expf(-b2f(ee[idx]));
    float aval = rv * u_i * kv_;
    aval += __shfl_xor(aval, 1);
    aval += __shfl_xor(aval, 2);
    aval += __shfl_xor(aval, 4);
    aval += __shfl_xor(aval, 8);
    aval += __shfl_xor(aval, 16);
    float4* cur = buf[t & 1];
    if (!half) cur[i] = make_float4(rv, kv_, dv, 0.f);
    __syncthreads();
    float p = 0.f;
    #pragma unroll
    for (int jj = 0; jj < 16; ++jj) {
      float4 q = cur[(half << 4) + jj];
      p += q.x * S[jj];
      S[jj] = fmaf(q.z, S[jj], q.y * vv);
    }
    p += __shfl_xor(p, 32);
    if (!half) y[idx] = f2b(p + aval * vv);
  }
}

// ---------------------------------------------------------------------------
// groupnorm over HS=32, * ln_w + ln_b, * silu(g) -> z bf16
// ---------------------------------------------------------------------------
__global__ __launch_bounds__(256) void gnorm_kernel(
    const bf16* __restrict__ y, const bf16* __restrict__ g,
    const float* __restrict__ lnw, const float* __restrict__ lnb,
    bf16* __restrict__ z) {
  int grp = blockIdx.x * 8 + (threadIdx.x >> 5);
  int i = threadIdx.x & 31;
  int token = grp >> 4, h = grp & 15;
  size_t idx = (size_t)token * C_ + h * HS_ + i;
  float yv = b2f(y[idx]);
  float mu = yv;
  mu += __shfl_xor(mu, 1); mu += __shfl_xor(mu, 2); mu += __shfl_xor(mu, 4);
  mu += __shfl_xor(mu, 8); mu += __shfl_xor(mu, 16);
  mu *= (1.f / 32.f);
  float d = yv - mu;
  float var = d * d;
  var += __shfl_xor(var, 1); var += __shfl_xor(var, 2); var += __shfl_xor(var, 4);
  var += __shfl_xor(var, 8); var += __shfl_xor(var, 16);
  var *= (1.f / 32.f);
  float yn = d * rsqrtf(var + 1e-5f);
  int c = h * HS_ + i;
  float outv = (yn * lnw[c] + lnb[c]) * b2f(g[idx]);
  z[idx] = f2b(outv);
}

// ---------------------------------------------------------------------------
extern "C" void kernel_launch(void* const* d_in, const int* in_sizes, int n_in,
                              void* d_out, int out_size, void* d_ws, size_t ws_size,
                              hipStream_t stream) {
  (void)in_sizes; (void)n_in; (void)out_size; (void)ws_size;
  const float* x      = (const float*)d_in[0];
  const float* tmx    = (const float*)d_in[1];
  const float* tmw    = (const float*)d_in[2];
  const float* tmk    = (const float*)d_in[3];
  const float* tmv    = (const float*)d_in[4];
  const float* tmr    = (const float*)d_in[5];
  const float* tmg    = (const float*)d_in[6];
  const float* w1     = (const float*)d_in[7];
  const float* w2     = (const float*)d_in[8];
  const float* tdecay = (const float*)d_in[9];
  const float* wd1    = (const float*)d_in[10];
  const float* wd2    = (const float*)d_in[11];
  const float* faaaa  = (const float*)d_in[12];
  const float* Wr     = (const float*)d_in[13];
  const float* Wk     = (const float*)d_in[14];
  const float* Wv     = (const float*)d_in[15];
  const float* Wg     = (const float*)d_in[16];
  const float* Wo     = (const float*)d_in[17];
  const float* Wo_    = Wo;
  const float* lnw    = (const float*)d_in[18];
  const float* lnb    = (const float*)d_in[19];
  float* out = (float*)d_out;

  // workspace layout — peak ~110.5 MB (ws known-safe >= 119.25 MB)
  char* w8 = (char*)d_ws;
  const size_t MB = 1024ull * 1024ull;
  bf16*  mixbuf = (bf16*)(w8);              // [0,16) staging: xxx/xw/xr/xk/xv/y
  bf16*  rb     = (bf16*)(w8 + 16 * MB);
  bf16*  kb     = (bf16*)(w8 + 32 * MB);
  bf16*  vb     = (bf16*)(w8 + 48 * MB);
  bf16*  ee     = (bf16*)(w8 + 64 * MB);    // e = exp(w)
  bf16*  mix5p  = (bf16*)(w8 + 80 * MB);    // [16384][192] bf16, 6 MB
  bf16*  h1     = (bf16*)(w8 + 86 * MB);    // [16384][64] bf16, 2 MB
  float* st     = (float*)(w8 + 88 * MB);   // chunk states, 16.5 MB
  bf16*  Wrb    = (bf16*)(w8 + 105 * MB);   // 1 MB each (hi + lo)
  bf16*  Wkb    = Wrb + 2 * WSZ_;
  bf16*  Wvb    = Wkb + 2 * WSZ_;
  bf16*  Wgb    = Wvb + 2 * WSZ_;
  bf16*  Wob    = Wgb + 2 * WSZ_;
  bf16*  w1p    = Wob + 2 * WSZ_;           // [192][512]
  bf16*  wd1p   = w1p + 192 * 512;          // [64][512]
  bf16*  yb     = mixbuf;                   // after xv consumed
  bf16*  xgb    = kb;                       // after wkv
  bf16*  gb     = vb;                       // after wkv
  bf16*  zb     = rb;                       // after wkv

  // weight prep (hi/lo split for the five big projections)
  conv_split_kernel<<<1024, 256, 0, stream>>>(Wr, Wrb, WSZ_);
  conv_split_kernel<<<1024, 256, 0, stream>>>(Wk, Wkb, WSZ_);
  conv_split_kernel<<<1024, 256, 0, stream>>>(Wv, Wvb, WSZ_);
  conv_split_kernel<<<1024, 256, 0, stream>>>(Wg, Wgb, WSZ_);
  conv_split_kernel<<<1024, 256, 0, stream>>>(Wo_, Wob, WSZ_);
  conv_t_kernel<<<384, 256, 0, stream>>>(w1, w1p, 160);    // -> [192][512]
  conv_t_kernel<<<128, 256, 0, stream>>>(wd1, wd1p, 64);   // -> [64][512]

  // mix5p = tanh(xxx @ w1p^T)
  prep_kernel<<<(BT_ * C_) / 256, 256, 0, stream>>>(x, tmx, mixbuf);
  mfma_gemm_kernel<64, 3, 0><<<dim3(128, 3), 256, 0, stream>>>(mixbuf, w1p, mix5p, 192);
  // w-pass: xw -> h1 = tanh(xw @ wd1^T) -> ee = exp(td + h1 @ wd2)
  mixf_kernel<<<BT_ / 8, 512, 0, stream>>>(mix5p, w2, x, tmw, mixbuf, 0);
  mfma_gemm_kernel<64, 3, 0><<<dim3(128, 1), 256, 0, stream>>>(mixbuf, wd1p, h1, 64);
  decay_kernel<<<BT_ / 8, 512, 0, stream>>>(h1, wd2, tdecay, ee);
  // r/k/v projections (split weights)
  dim3 gg(128, 4);
  mixf_kernel<<<BT_ / 8, 512, 0, stream>>>(mix5p, w2, x, tmr, mixbuf, 3);
  mfma_gemm_kernel<128, 0, 1><<<gg, 256, 0, stream>>>(mixbuf, Wrb, rb, C_);
  mixf_kernel<<<BT_ / 8, 512, 0, stream>>>(mix5p, w2, x, tmk, mixbuf, 1);
  mfma_gemm_kernel<128, 0, 1><<<gg, 256, 0, stream>>>(mixbuf, Wkb, kb, C_);
  mixf_kernel<<<BT_ / 8, 512, 0, stream>>>(mix5p, w2, x, tmv, mixbuf, 2);
  mfma_gemm_kernel<128, 0, 1><<<gg, 256, 0, stream>>>(mixbuf, Wvb, vb, C_);
  // chunk-parallel WKV6 scan
  wkv_partial_kernel<<<B_ * H_ * NC_, 64, 0, stream>>>(kb, vb, ee, st);
  wkv_stitch_kernel<<<B_ * H_, 64, 0, stream>>>(st);
  wkv_final_kernel<<<B_ * H_ * NC_, 64, 0, stream>>>(rb, kb, vb, ee, faaaa, st, yb);
  // g-pass (kb/vb dead), silu fused in GEMM epilogue
  mixf_kernel<<<BT_ / 8, 512, 0, stream>>>(mix5p, w2, x, tmg, xgb, 4);
  mfma_gemm_kernel<128, 1, 1><<<gg, 256, 0, stream>>>(xgb, Wgb, gb, C_);
  // groupnorm * g -> zb, then output projection (fp32 out)
  gnorm_kernel<<<(BT_ * H_) / 8, 256, 0, stream>>>(yb, gb, lnw, lnb, zb);
  mfma_gemm_kernel<128, 2, 1><<<gg, 256, 0, stream>>>(zb, Wob, out, C_);
}

// Round 9
// 802.338 us; speedup vs baseline: 4.1499x; 1.0717x over previous
//
#include <hip/hip_runtime.h>
#include <hip/hip_bf16.h>

#define B_ 8
#define T_ 2048
#define C_ 512
#define H_ 16
#define HS_ 32
#define BT_ (B_*T_)   // 16384 tokens
#define CL_ 64        // scan chunk length
#define NC_ (T_/CL_)  // 32 chunks
#define STF_ 1056     // floats per (bh,chunk) state: 1024 S + 32 P
#define WSZ_ 262144   // elements per 512x512 weight

typedef __hip_bfloat16 bf16;
typedef __attribute__((ext_vector_type(8))) short short8;
typedef __attribute__((ext_vector_type(4))) float f32x4;

__device__ __forceinline__ float b2f(bf16 v) { return __bfloat162float(v); }
__device__ __forceinline__ bf16 f2b(float v) { return __float2bfloat16(v); }

// ---------------------------------------------------------------------------
// Weight prep. split: W -> hi bf16 + lo bf16 (restores fp32 to ~2^-17 rel).
// ---------------------------------------------------------------------------
__global__ __launch_bounds__(256) void conv_split_kernel(
    const float* __restrict__ src, bf16* __restrict__ dst, int n) {
  int i = blockIdx.x * 256 + threadIdx.x;
  if (i < n) {
    float s = src[i];
    bf16 hi = f2b(s);
    dst[i] = hi;
    dst[n + i] = f2b(s - b2f(hi));
  }
}
// src fp32 [C_][nsrc]  ->  dst bf16 [npad][C_], rows >= nsrc zero-filled
__global__ __launch_bounds__(256) void conv_t_kernel(
    const float* __restrict__ src, bf16* __restrict__ dst, int nsrc) {
  int i = blockIdx.x * 256 + threadIdx.x;   // over npad*C_
  int n = i >> 9, k = i & (C_ - 1);
  dst[i] = f2b(n < nsrc ? src[k * nsrc + n] : 0.f);
}

// ---------------------------------------------------------------------------
// prep: xxx = x + (xshift - x)*maa_x   (bf16 out)
// ---------------------------------------------------------------------------
__global__ __launch_bounds__(256) void prep_kernel(
    const float* __restrict__ x, const float* __restrict__ tmx,
    bf16* __restrict__ xxx) {
  int idx = blockIdx.x * 256 + threadIdx.x;
  int c = idx & (C_ - 1);
  int t = (idx >> 9) & (T_ - 1);
  float xc = x[idx];
  float xp = (t == 0) ? 0.f : x[idx - C_];
  xxx[idx] = f2b(xc + (xp - xc) * tmx[c]);
}

// ---------------------------------------------------------------------------
// MFMA GEMM: O = act(A @ Bw^T). BM=128, BK=32, 256 thr. (verified round 8)
// MODE: 0 bf16; 1 bf16+silu; 2 fp32; 3 bf16+tanh.  N = output stride.
// ---------------------------------------------------------------------------
template<int BN, int MODE, int SPLIT>
__global__ __launch_bounds__(256) void mfma_gemm_kernel(
    const bf16* __restrict__ A, const bf16* __restrict__ Bw,
    void* __restrict__ O, int N) {
  constexpr int BM = 128, BK = 32;
  constexpr int AE = BM * BK / 8;
  constexpr int BE = BN * BK / 8;
  __shared__ short8 Asm[AE];
  __shared__ short8 Bsm[BE];
  __shared__ short8 Lsm[SPLIT ? BE : 1];
  const int tid = threadIdx.x;
  const int lane = tid & 63;
  const int wave = tid >> 6;
  const int m0 = blockIdx.x * BM;
  const int n0 = blockIdx.y * BN;
  const int wm = (BN == 128) ? (wave >> 1) * 64 : wave * 32;
  const int wn = (BN == 128) ? (wave & 1) * 64 : 0;
  constexpr int MT = (BN == 128) ? 4 : 2;
  constexpr int NT = 4;
  f32x4 acc[MT][NT] = {};
  const int e0 = tid, e1 = tid + 256;
  const int r0 = ((e0 >> 6) << 4) | (e0 & 15), q0 = (e0 >> 4) & 3;
  const int r1 = ((e1 >> 6) << 4) | (e1 & 15), q1 = (e1 >> 4) & 3;
  const unsigned short* Au = (const unsigned short*)A;
  const unsigned short* Bu = (const unsigned short*)Bw;
  const unsigned short* Lu = Bu + (SPLIT ? WSZ_ : 0);
  for (int k0 = 0; k0 < C_; k0 += BK) {
    short8 a0 = *(const short8*)&Au[(size_t)(m0 + r0) * C_ + k0 + q0 * 8];
    short8 a1 = *(const short8*)&Au[(size_t)(m0 + r1) * C_ + k0 + q1 * 8];
    short8 b0 = *(const short8*)&Bu[(size_t)(n0 + r0) * C_ + k0 + q0 * 8];
    short8 b1, l0, l1;
    if constexpr (BN == 128)
      b1 = *(const short8*)&Bu[(size_t)(n0 + r1) * C_ + k0 + q1 * 8];
    if constexpr (SPLIT) {
      l0 = *(const short8*)&Lu[(size_t)(n0 + r0) * C_ + k0 + q0 * 8];
      if constexpr (BN == 128)
        l1 = *(const short8*)&Lu[(size_t)(n0 + r1) * C_ + k0 + q1 * 8];
    }
    __syncthreads();
    Asm[e0] = a0; Asm[e1] = a1;
    Bsm[e0] = b0;
    if constexpr (BN == 128) Bsm[e1] = b1;
    if constexpr (SPLIT) {
      Lsm[e0] = l0;
      if constexpr (BN == 128) Lsm[e1] = l1;
    }
    __syncthreads();
    short8 af[MT], bh[NT];
    #pragma unroll
    for (int mt = 0; mt < MT; ++mt) af[mt] = Asm[((wm >> 4) + mt) * 64 + lane];
    #pragma unroll
    for (int nt = 0; nt < NT; ++nt) bh[nt] = Bsm[((wn >> 4) + nt) * 64 + lane];
    #pragma unroll
    for (int mt = 0; mt < MT; ++mt)
      #pragma unroll
      for (int nt = 0; nt < NT; ++nt)
        acc[mt][nt] = __builtin_amdgcn_mfma_f32_16x16x32_bf16(
            af[mt], bh[nt], acc[mt][nt], 0, 0, 0);
    if constexpr (SPLIT) {
      short8 bl[NT];
      #pragma unroll
      for (int nt = 0; nt < NT; ++nt) bl[nt] = Lsm[((wn >> 4) + nt) * 64 + lane];
      #pragma unroll
      for (int mt = 0; mt < MT; ++mt)
        #pragma unroll
        for (int nt = 0; nt < NT; ++nt)
          acc[mt][nt] = __builtin_amdgcn_mfma_f32_16x16x32_bf16(
              af[mt], bl[nt], acc[mt][nt], 0, 0, 0);
    }
  }
  const int col = lane & 15, qr = lane >> 4;
  #pragma unroll
  for (int mt = 0; mt < MT; ++mt) {
    int mrow = m0 + wm + mt * 16 + qr * 4;
    #pragma unroll
    for (int nt = 0; nt < NT; ++nt) {
      int nc = n0 + wn + nt * 16 + col;
      #pragma unroll
      for (int r = 0; r < 4; ++r) {
        float v = acc[mt][nt][r];
        if (MODE == 1) v = v / (1.f + __expf(-v));
        if (MODE == 3) v = tanhf(v);
        size_t oi = (size_t)(mrow + r) * N + nc;
        if (MODE == 2) ((float*)O)[oi] = v;
        else           ((bf16*)O)[oi] = f2b(v);
      }
    }
  }
}

// ---------------------------------------------------------------------------
// mix pass (unchanged, verified)
// ---------------------------------------------------------------------------
__global__ __launch_bounds__(512) void mixf_kernel(
    const bf16* __restrict__ mix5, const float* __restrict__ w2,
    const float* __restrict__ x, const float* __restrict__ tmf,
    bf16* __restrict__ xf, int f) {
  __shared__ float M[8][32];
  int row0 = blockIdx.x * 8;
  if (threadIdx.x < 256) {
    int rr = threadIdx.x >> 5, d = threadIdx.x & 31;
    M[rr][d] = b2f(mix5[(size_t)(row0 + rr) * 192 + f * 32 + d]);
  }
  __syncthreads();
  int c = threadIdx.x;
  float acc[8] = {0.f,0.f,0.f,0.f,0.f,0.f,0.f,0.f};
  for (int d = 0; d < 32; ++d) {
    float wv = w2[(size_t)(f * 32 + d) * C_ + c];
    #pragma unroll
    for (int r = 0; r < 8; ++r) acc[r] += M[r][d] * wv;
  }
  float tv = tmf[c];
  #pragma unroll
  for (int r = 0; r < 8; ++r) {
    int row = row0 + r;
    int t = row & (T_ - 1);
    size_t idx = (size_t)row * C_ + c;
    float xc = x[idx];
    float xp = (t == 0) ? 0.f : x[idx - C_];
    xf[idx] = f2b(xc + (xp - xc) * (tv + acc[r]));
  }
}

// ---------------------------------------------------------------------------
// decay (unchanged, verified)
// ---------------------------------------------------------------------------
__global__ __launch_bounds__(512) void decay_kernel(
    const bf16* __restrict__ h1, const float* __restrict__ wd2,
    const float* __restrict__ tdecay, bf16* __restrict__ ee) {
  __shared__ float Hs[8][64];
  int row0 = blockIdx.x * 8;
  {
    int e = threadIdx.x;
    Hs[e >> 6][e & 63] = b2f(h1[(size_t)(row0 + (e >> 6)) * 64 + (e & 63)]);
  }
  __syncthreads();
  int c = threadIdx.x;
  float acc[8] = {0.f,0.f,0.f,0.f,0.f,0.f,0.f,0.f};
  for (int j = 0; j < 64; ++j) {
    float wv = wd2[j * C_ + c];
    #pragma unroll
    for (int r = 0; r < 8; ++r) acc[r] += Hs[r][j] * wv;
  }
  float td = tdecay[c];
  #pragma unroll
  for (int r = 0; r < 8; ++r)
    ee[(size_t)(row0 + r) * C_ + c] = f2b(expf(td + acc[r]));
}

// ---------------------------------------------------------------------------
// WKV6 chunked scan — MFMA form.  One wave per (b,h,chunk).
// L[t][j] = sum_{u<t} -e[u][j];  A_t = exp(L).  All MFMA 16x16x32 bf16.
// Pass A: Sc^T[i][j] = sum_s V[s][i]*K[s][j]*exp(Ltot-L[s+1]); P[j]=exp(Ltot).
// ---------------------------------------------------------------------------
__global__ __launch_bounds__(64) void wkv_partial_mfma(
    const bf16* __restrict__ k, const bf16* __restrict__ v,
    const bf16* __restrict__ ee, float* __restrict__ st) {
  __shared__ __align__(16) char smem[17536];
  float* Lm  = (float*)smem;              // [65][32]
  bf16*  K2T = (bf16*)(smem + 8320);      // [32][72]
  bf16*  VT  = (bf16*)(smem + 12928);     // [32][72]
  int g = blockIdx.x;
  int bh = g >> 5, c = g & (NC_ - 1);
  int b = bh >> 4, h = bh & 15;
  int lane = threadIdx.x;
  size_t gbase = (size_t)b * T_ * C_ + (size_t)(c * CL_) * C_ + h * HS_;
  if (lane < 32) {                        // prefix log-decay
    int j = lane;
    float L = 0.f;
    for (int t = 0; t < CL_; ++t) {
      Lm[t * 32 + j] = L;
      L -= b2f(ee[gbase + (size_t)t * C_ + j]);
    }
    Lm[64 * 32 + j] = L;                  // Ltot
  }
  __syncthreads();
  for (int it = 0; it < 32; ++it) {       // stage K2T, VT
    int t = it * 2 + (lane >> 5);
    int ch = lane & 31;
    size_t gi = gbase + (size_t)t * C_ + ch;
    float Lt1  = Lm[(t + 1) * 32 + ch];
    float Ltot = Lm[64 * 32 + ch];
    K2T[ch * 72 + t] = f2b(b2f(k[gi]) * __expf(Ltot - Lt1));
    VT [ch * 72 + t] = v[gi];
  }
  __syncthreads();
  const int fl = lane & 15, q = lane >> 4;
  f32x4 accS[2][2] = {};
  #pragma unroll
  for (int kc = 0; kc < 2; ++kc) {
    short8 av[2], bk[2];
    #pragma unroll
    for (int mt = 0; mt < 2; ++mt)
      av[mt] = *(const short8*)(VT + (mt * 16 + fl) * 72 + kc * 32 + q * 8);
    #pragma unroll
    for (int nt = 0; nt < 2; ++nt)
      bk[nt] = *(const short8*)(K2T + (nt * 16 + fl) * 72 + kc * 32 + q * 8);
    #pragma unroll
    for (int mt = 0; mt < 2; ++mt)
      #pragma unroll
      for (int nt = 0; nt < 2; ++nt)
        accS[mt][nt] = __builtin_amdgcn_mfma_f32_16x16x32_bf16(
            av[mt], bk[nt], accS[mt][nt], 0, 0, 0);
  }
  size_t sbase = (size_t)g * STF_;
  #pragma unroll
  for (int mt = 0; mt < 2; ++mt)
    #pragma unroll
    for (int nt = 0; nt < 2; ++nt)
      #pragma unroll
      for (int r = 0; r < 4; ++r)
        st[sbase + (size_t)(mt * 16 + q * 4 + r) * 32 + nt * 16 + fl] =
            accS[mt][nt][r];
  if (lane < 32) st[sbase + 1024 + lane] = __expf(Lm[64 * 32 + lane]);
}

// Pass 2: stitch (unchanged, verified) — overwrite slot c with initial state.
__global__ __launch_bounds__(64) void wkv_stitch_kernel(float* __restrict__ st) {
  int bh = blockIdx.x;
  int lane = threadIdx.x;
  int i = lane & 31, half = lane >> 5;
  float R[16];
  #pragma unroll
  for (int jj = 0; jj < 16; ++jj) R[jj] = 0.f;
  for (int c = 0; c < NC_; ++c) {
    size_t s = ((size_t)bh * NC_ + c) * STF_;
    float* sp = st + s + i * 32 + (half << 4);
    float Sc[16];
    float4* sc4 = reinterpret_cast<float4*>(Sc);
    float4* sp4 = reinterpret_cast<float4*>(sp);
    #pragma unroll
    for (int q = 0; q < 4; ++q) sc4[q] = sp4[q];
    float Pj[16];
    #pragma unroll
    for (int jj = 0; jj < 16; ++jj) Pj[jj] = st[s + 1024 + (half << 4) + jj];
    float4* r4 = reinterpret_cast<float4*>(R);
    #pragma unroll
    for (int q = 0; q < 4; ++q) sp4[q] = r4[q];
    #pragma unroll
    for (int jj = 0; jj < 16; ++jj) R[jj] = fmaf(Pj[jj], R[jj], Sc[jj]);
  }
}

// Pass 3: y = (R.A)S0^T + mask[(R.A)(K/A')^T]V + diag(sum r u k)V — MFMA.
__global__ __launch_bounds__(64) void wkv_final_mfma(
    const bf16* __restrict__ r, const bf16* __restrict__ k,
    const bf16* __restrict__ v, const bf16* __restrict__ ee,
    const float* __restrict__ faaaa, const float* __restrict__ st,
    bf16* __restrict__ y) {
  __shared__ __align__(16) char smem[29440];
  float* Lm = (float*)smem;               // [65][32] — aliased by Pm later
  bf16*  Pm = (bf16*)smem;                // [64][72]
  bf16*  RA = (bf16*)(smem + 9216);       // [64][40]
  bf16*  Kd = (bf16*)(smem + 14336);      // [64][40]
  bf16*  VT = (bf16*)(smem + 19456);      // [32][72]
  bf16*  Sh = (bf16*)(smem + 24064);      // [32][40]
  bf16*  Sl = (bf16*)(smem + 26624);      // [32][40]
  float* bon = (float*)(smem + 29184);    // [64]
  int g = blockIdx.x;
  int bh = g >> 5, c = g & (NC_ - 1);
  int b = bh >> 4, h = bh & 15;
  int lane = threadIdx.x;
  size_t gbase = (size_t)b * T_ * C_ + (size_t)(c * CL_) * C_ + h * HS_;
  size_t sbase = (size_t)g * STF_;
  if (lane < 32) {                        // prefix log-decay
    int j = lane;
    float L = 0.f;
    for (int t = 0; t < CL_; ++t) {
      Lm[t * 32 + j] = L;
      L -= b2f(ee[gbase + (size_t)t * C_ + j]);
    }
    Lm[64 * 32 + j] = L;
  }
  // stage S0 hi/lo (independent of Lm)
  for (int it = 0; it < 16; ++it) {
    int idx = it * 64 + lane;
    int i = idx >> 5, j = idx & 31;
    float s = st[sbase + idx];
    bf16 hi = f2b(s);
    Sh[i * 40 + j] = hi;
    Sl[i * 40 + j] = f2b(s - b2f(hi));
  }
  float u_j = faaaa[h * HS_ + (lane & 31)];
  __syncthreads();
  for (int it = 0; it < 32; ++it) {       // stage RA, Kd, VT, bonus
    int t = it * 2 + (lane >> 5);
    int ch = lane & 31;
    size_t gi = gbase + (size_t)t * C_ + ch;
    float rv = b2f(r[gi]), kv = b2f(k[gi]);
    float Lt  = Lm[t * 32 + ch];
    float Lt1 = Lm[(t + 1) * 32 + ch];
    RA[t * 40 + ch] = f2b(rv * __expf(Lt));
    Kd[t * 40 + ch] = f2b(kv * __expf(-Lt1));
    VT[ch * 72 + t] = v[gi];
    float pb = rv * u_j * kv;
    pb += __shfl_xor(pb, 1); pb += __shfl_xor(pb, 2);
    pb += __shfl_xor(pb, 4); pb += __shfl_xor(pb, 8);
    pb += __shfl_xor(pb, 16);
    if (ch == 0) bon[t] = pb;
  }
  __syncthreads();
  const int fl = lane & 15, q = lane >> 4;
  short8 afr[4];
  #pragma unroll
  for (int mt = 0; mt < 4; ++mt)
    afr[mt] = *(const short8*)(RA + (mt * 16 + fl) * 40 + q * 8);
  f32x4 accY[4][2] = {};
  {                                        // inter-chunk: (R.A) @ S0^T (split)
    short8 sh[2], sl[2];
    #pragma unroll
    for (int nt = 0; nt < 2; ++nt) {
      sh[nt] = *(const short8*)(Sh + (nt * 16 + fl) * 40 + q * 8);
      sl[nt] = *(const short8*)(Sl + (nt * 16 + fl) * 40 + q * 8);
    }
    #pragma unroll
    for (int mt = 0; mt < 4; ++mt)
      #pragma unroll
      for (int nt = 0; nt < 2; ++nt) {
        accY[mt][nt] = __builtin_amdgcn_mfma_f32_16x16x32_bf16(
            afr[mt], sh[nt], accY[mt][nt], 0, 0, 0);
        accY[mt][nt] = __builtin_amdgcn_mfma_f32_16x16x32_bf16(
            afr[mt], sl[nt], accY[mt][nt], 0, 0, 0);
      }
  }
  f32x4 accP[4][4] = {};
  {                                        // P = (R.A)(K/A')^T
    short8 bk[4];
    #pragma unroll
    for (int s4 = 0; s4 < 4; ++s4)
      bk[s4] = *(const short8*)(Kd + (s4 * 16 + fl) * 40 + q * 8);
    #pragma unroll
    for (int mt = 0; mt < 4; ++mt)
      #pragma unroll
      for (int s4 = 0; s4 < 4; ++s4)
        accP[mt][s4] = __builtin_amdgcn_mfma_f32_16x16x32_bf16(
            afr[mt], bk[s4], accP[mt][s4], 0, 0, 0);
  }
  __syncthreads();                         // Lm dead -> safe to write Pm
  #pragma unroll
  for (int mt = 0; mt < 4; ++mt)
    #pragma unroll
    for (int s4 = 0; s4 < 4; ++s4)
      #pragma unroll
      for (int rr = 0; rr < 4; ++rr) {
        int t = mt * 16 + q * 4 + rr;
        int s = s4 * 16 + fl;
        float pv = accP[mt][s4][rr];
        float bv = bon[t];
        pv = (s < t) ? pv : ((s == t) ? bv : 0.f);
        Pm[t * 72 + s] = f2b(pv);
      }
  __syncthreads();
  {                                        // Y += P @ V
    short8 bv[2][2];
    #pragma unroll
    for (int nt = 0; nt < 2; ++nt)
      #pragma unroll
      for (int kc = 0; kc < 2; ++kc)
        bv[nt][kc] = *(const short8*)(VT + (nt * 16 + fl) * 72 + kc * 32 + q * 8);
    #pragma unroll
    for (int mt = 0; mt < 4; ++mt)
      #pragma unroll
      for (int kc = 0; kc < 2; ++kc) {
        short8 ap = *(const short8*)(Pm + (mt * 16 + fl) * 72 + kc * 32 + q * 8);
        #pragma unroll
        for (int nt = 0; nt < 2; ++nt)
          accY[mt][nt] = __builtin_amdgcn_mfma_f32_16x16x32_bf16(
              ap, bv[nt][kc], accY[mt][nt], 0, 0, 0);
      }
  }
  #pragma unroll
  for (int mt = 0; mt < 4; ++mt)
    #pragma unroll
    for (int nt = 0; nt < 2; ++nt)
      #pragma unroll
      for (int rr = 0; rr < 4; ++rr) {
        int t = mt * 16 + q * 4 + rr;
        int i = nt * 16 + fl;
        y[gbase + (size_t)t * C_ + i] = f2b(accY[mt][nt][rr]);
      }
}

// ---------------------------------------------------------------------------
// groupnorm over HS=32, * ln_w + ln_b, * silu(g) -> z bf16  (unchanged)
// ---------------------------------------------------------------------------
__global__ __launch_bounds__(256) void gnorm_kernel(
    const bf16* __restrict__ y, const bf16* __restrict__ g,
    const float* __restrict__ lnw, const float* __restrict__ lnb,
    bf16* __restrict__ z) {
  int grp = blockIdx.x * 8 + (threadIdx.x >> 5);
  int i = threadIdx.x & 31;
  int token = grp >> 4, h = grp & 15;
  size_t idx = (size_t)token * C_ + h * HS_ + i;
  float yv = b2f(y[idx]);
  float mu = yv;
  mu += __shfl_xor(mu, 1); mu += __shfl_xor(mu, 2); mu += __shfl_xor(mu, 4);
  mu += __shfl_xor(mu, 8); mu += __shfl_xor(mu, 16);
  mu *= (1.f / 32.f);
  float d = yv - mu;
  float var = d * d;
  var += __shfl_xor(var, 1); var += __shfl_xor(var, 2); var += __shfl_xor(var, 4);
  var += __shfl_xor(var, 8); var += __shfl_xor(var, 16);
  var *= (1.f / 32.f);
  float yn = d * rsqrtf(var + 1e-5f);
  int c = h * HS_ + i;
  float outv = (yn * lnw[c] + lnb[c]) * b2f(g[idx]);
  z[idx] = f2b(outv);
}

// ---------------------------------------------------------------------------
extern "C" void kernel_launch(void* const* d_in, const int* in_sizes, int n_in,
                              void* d_out, int out_size, void* d_ws, size_t ws_size,
                              hipStream_t stream) {
  (void)in_sizes; (void)n_in; (void)out_size; (void)ws_size;
  const float* x      = (const float*)d_in[0];
  const float* tmx    = (const float*)d_in[1];
  const float* tmw    = (const float*)d_in[2];
  const float* tmk    = (const float*)d_in[3];
  const float* tmv    = (const float*)d_in[4];
  const float* tmr    = (const float*)d_in[5];
  const float* tmg    = (const float*)d_in[6];
  const float* w1     = (const float*)d_in[7];
  const float* w2     = (const float*)d_in[8];
  const float* tdecay = (const float*)d_in[9];
  const float* wd1    = (const float*)d_in[10];
  const float* wd2    = (const float*)d_in[11];
  const float* faaaa  = (const float*)d_in[12];
  const float* Wr     = (const float*)d_in[13];
  const float* Wk     = (const float*)d_in[14];
  const float* Wv     = (const float*)d_in[15];
  const float* Wg     = (const float*)d_in[16];
  const float* Wo     = (const float*)d_in[17];
  const float* lnw    = (const float*)d_in[18];
  const float* lnb    = (const float*)d_in[19];
  float* out = (float*)d_out;

  // workspace layout — peak ~110.5 MB (ws known-safe >= 119.25 MB)
  char* w8 = (char*)d_ws;
  const size_t MB = 1024ull * 1024ull;
  bf16*  mixbuf = (bf16*)(w8);
  bf16*  rb     = (bf16*)(w8 + 16 * MB);
  bf16*  kb     = (bf16*)(w8 + 32 * MB);
  bf16*  vb     = (bf16*)(w8 + 48 * MB);
  bf16*  ee     = (bf16*)(w8 + 64 * MB);
  bf16*  mix5p  = (bf16*)(w8 + 80 * MB);
  bf16*  h1     = (bf16*)(w8 + 86 * MB);
  float* st     = (float*)(w8 + 88 * MB);
  bf16*  Wrb    = (bf16*)(w8 + 105 * MB);
  bf16*  Wkb    = Wrb + 2 * WSZ_;
  bf16*  Wvb    = Wkb + 2 * WSZ_;
  bf16*  Wgb    = Wvb + 2 * WSZ_;
  bf16*  Wob    = Wgb + 2 * WSZ_;
  bf16*  w1p    = Wob + 2 * WSZ_;
  bf16*  wd1p   = w1p + 192 * 512;
  bf16*  yb     = mixbuf;
  bf16*  xgb    = kb;
  bf16*  gb     = vb;
  bf16*  zb     = rb;

  conv_split_kernel<<<1024, 256, 0, stream>>>(Wr, Wrb, WSZ_);
  conv_split_kernel<<<1024, 256, 0, stream>>>(Wk, Wkb, WSZ_);
  conv_split_kernel<<<1024, 256, 0, stream>>>(Wv, Wvb, WSZ_);
  conv_split_kernel<<<1024, 256, 0, stream>>>(Wg, Wgb, WSZ_);
  conv_split_kernel<<<1024, 256, 0, stream>>>(Wo, Wob, WSZ_);
  conv_t_kernel<<<384, 256, 0, stream>>>(w1, w1p, 160);
  conv_t_kernel<<<128, 256, 0, stream>>>(wd1, wd1p, 64);

  prep_kernel<<<(BT_ * C_) / 256, 256, 0, stream>>>(x, tmx, mixbuf);
  mfma_gemm_kernel<64, 3, 0><<<dim3(128, 3), 256, 0, stream>>>(mixbuf, w1p, mix5p, 192);
  mixf_kernel<<<BT_ / 8, 512, 0, stream>>>(mix5p, w2, x, tmw, mixbuf, 0);
  mfma_gemm_kernel<64, 3, 0><<<dim3(128, 1), 256, 0, stream>>>(mixbuf, wd1p, h1, 64);
  decay_kernel<<<BT_ / 8, 512, 0, stream>>>(h1, wd2, tdecay, ee);
  dim3 gg(128, 4);
  mixf_kernel<<<BT_ / 8, 512, 0, stream>>>(mix5p, w2, x, tmr, mixbuf, 3);
  mfma_gemm_kernel<128, 0, 1><<<gg, 256, 0, stream>>>(mixbuf, Wrb, rb, C_);
  mixf_kernel<<<BT_ / 8, 512, 0, stream>>>(mix5p, w2, x, tmk, mixbuf, 1);
  mfma_gemm_kernel<128, 0, 1><<<gg, 256, 0, stream>>>(mixbuf, Wkb, kb, C_);
  mixf_kernel<<<BT_ / 8, 512, 0, stream>>>(mix5p, w2, x, tmv, mixbuf, 2);
  mfma_gemm_kernel<128, 0, 1><<<gg, 256, 0, stream>>>(mixbuf, Wvb, vb, C_);
  // chunk-parallel WKV6 scan — MFMA form
  wkv_partial_mfma<<<B_ * H_ * NC_, 64, 0, stream>>>(kb, vb, ee, st);
  wkv_stitch_kernel<<<B_ * H_, 64, 0, stream>>>(st);
  wkv_final_mfma<<<B_ * H_ * NC_, 64, 0, stream>>>(rb, kb, vb, ee, faaaa, st, yb);
  mixf_kernel<<<BT_ / 8, 512, 0, stream>>>(mix5p, w2, x, tmg, xgb, 4);
  mfma_gemm_kernel<128, 1, 1><<<gg, 256, 0, stream>>>(xgb, Wgb, gb, C_);
  gnorm_kernel<<<(BT_ * H_) / 8, 256, 0, stream>>>(yb, gb, lnw, lnb, zb);
  mfma_gemm_kernel<128, 2, 1><<<gg, 256, 0, stream>>>(zb, Wob, out, C_);
}

// Round 10
// 558.256 us; speedup vs baseline: 5.9643x; 1.4372x over previous
//
#include <hip/hip_runtime.h>
#include <hip/hip_bf16.h>

#define B_ 8
#define T_ 2048
#define C_ 512
#define H_ 16
#define HS_ 32
#define BT_ (B_*T_)   // 16384 tokens
#define CL_ 64        // scan chunk length
#define NC_ (T_/CL_)  // 32 chunks
#define STF_ 1056     // floats per (bh,chunk) state: 1024 S + 32 P
#define WSZ_ 262144   // elements per 512x512 weight (2^18)

typedef __hip_bfloat16 bf16;
typedef __attribute__((ext_vector_type(8))) short short8;
typedef __attribute__((ext_vector_type(4))) float f32x4;

__device__ __forceinline__ float b2f(bf16 v) { return __bfloat162float(v); }
__device__ __forceinline__ bf16 f2b(float v) { return __float2bfloat16(v); }

// ---------------------------------------------------------------------------
// prep_combo: one launch does (a) xxx = x + (xshift-x)*maa_x, (b) hi/lo bf16
// split of the five 512x512 weights, (c) transpose+pad w1 -> [192][512] and
// wd1 -> [64][512].  Grid covers the concatenated index space exactly.
// ---------------------------------------------------------------------------
__global__ __launch_bounds__(256) void prep_combo_kernel(
    const float* __restrict__ x, const float* __restrict__ tmx,
    const float* __restrict__ Wr, const float* __restrict__ Wk,
    const float* __restrict__ Wv, const float* __restrict__ Wg,
    const float* __restrict__ Wo, const float* __restrict__ w1,
    const float* __restrict__ wd1,
    bf16* __restrict__ xxx, bf16* __restrict__ Wrb, bf16* __restrict__ Wkb,
    bf16* __restrict__ Wvb, bf16* __restrict__ Wgb, bf16* __restrict__ Wob,
    bf16* __restrict__ w1p, bf16* __restrict__ wd1p) {
  int idx = blockIdx.x * 256 + threadIdx.x;
  if (idx < BT_ * C_) {                       // token-shift mix input
    int c = idx & (C_ - 1);
    int t = (idx >> 9) & (T_ - 1);
    float xc = x[idx];
    float xp = (t == 0) ? 0.f : x[idx - C_];
    xxx[idx] = f2b(xc + (xp - xc) * tmx[c]);
    return;
  }
  idx -= BT_ * C_;
  if (idx < 5 * WSZ_) {                       // weight hi/lo split
    int w = idx >> 18;
    int i = idx & (WSZ_ - 1);
    const float* src = (w == 0) ? Wr : (w == 1) ? Wk : (w == 2) ? Wv
                     : (w == 3) ? Wg : Wo;
    bf16* dst = (w == 0) ? Wrb : (w == 1) ? Wkb : (w == 2) ? Wvb
              : (w == 3) ? Wgb : Wob;
    float s = src[i];
    bf16 hi = f2b(s);
    dst[i] = hi;
    dst[WSZ_ + i] = f2b(s - b2f(hi));
    return;
  }
  idx -= 5 * WSZ_;
  if (idx < 192 * 512) {                      // w1^T padded to 192 rows
    int n = idx >> 9, k = idx & (C_ - 1);
    w1p[idx] = f2b(n < 160 ? w1[k * 160 + n] : 0.f);
    return;
  }
  idx -= 192 * 512;
  {                                           // wd1^T [64][512]
    int n = idx >> 9, k = idx & (C_ - 1);
    wd1p[idx] = f2b(wd1[k * 64 + n]);
  }
}
#define PREP_N_ ((BT_*C_ + 5*WSZ_ + 192*512 + 64*512) / 256)   // 38400 blocks

// ---------------------------------------------------------------------------
// MFMA GEMM: O = act(A @ Bw^T). BM=128, BK=32, 256 thr. (verified round 8)
// MODE: 0 bf16; 1 bf16+silu; 2 fp32; 3 bf16+tanh.  N = output stride.
// ---------------------------------------------------------------------------
template<int BN, int MODE, int SPLIT>
__global__ __launch_bounds__(256) void mfma_gemm_kernel(
    const bf16* __restrict__ A, const bf16* __restrict__ Bw,
    void* __restrict__ O, int N) {
  constexpr int BM = 128, BK = 32;
  constexpr int AE = BM * BK / 8;
  constexpr int BE = BN * BK / 8;
  __shared__ short8 Asm[AE];
  __shared__ short8 Bsm[BE];
  __shared__ short8 Lsm[SPLIT ? BE : 1];
  const int tid = threadIdx.x;
  const int lane = tid & 63;
  const int wave = tid >> 6;
  const int m0 = blockIdx.x * BM;
  const int n0 = blockIdx.y * BN;
  const int wm = (BN == 128) ? (wave >> 1) * 64 : wave * 32;
  const int wn = (BN == 128) ? (wave & 1) * 64 : 0;
  constexpr int MT = (BN == 128) ? 4 : 2;
  constexpr int NT = 4;
  f32x4 acc[MT][NT] = {};
  const int e0 = tid, e1 = tid + 256;
  const int r0 = ((e0 >> 6) << 4) | (e0 & 15), q0 = (e0 >> 4) & 3;
  const int r1 = ((e1 >> 6) << 4) | (e1 & 15), q1 = (e1 >> 4) & 3;
  const unsigned short* Au = (const unsigned short*)A;
  const unsigned short* Bu = (const unsigned short*)Bw;
  const unsigned short* Lu = Bu + (SPLIT ? WSZ_ : 0);
  for (int k0 = 0; k0 < C_; k0 += BK) {
    short8 a0 = *(const short8*)&Au[(size_t)(m0 + r0) * C_ + k0 + q0 * 8];
    short8 a1 = *(const short8*)&Au[(size_t)(m0 + r1) * C_ + k0 + q1 * 8];
    short8 b0 = *(const short8*)&Bu[(size_t)(n0 + r0) * C_ + k0 + q0 * 8];
    short8 b1, l0, l1;
    if constexpr (BN == 128)
      b1 = *(const short8*)&Bu[(size_t)(n0 + r1) * C_ + k0 + q1 * 8];
    if constexpr (SPLIT) {
      l0 = *(const short8*)&Lu[(size_t)(n0 + r0) * C_ + k0 + q0 * 8];
      if constexpr (BN == 128)
        l1 = *(const short8*)&Lu[(size_t)(n0 + r1) * C_ + k0 + q1 * 8];
    }
    __syncthreads();
    Asm[e0] = a0; Asm[e1] = a1;
    Bsm[e0] = b0;
    if constexpr (BN == 128) Bsm[e1] = b1;
    if constexpr (SPLIT) {
      Lsm[e0] = l0;
      if constexpr (BN == 128) Lsm[e1] = l1;
    }
    __syncthreads();
    short8 af[MT], bh[NT];
    #pragma unroll
    for (int mt = 0; mt < MT; ++mt) af[mt] = Asm[((wm >> 4) + mt) * 64 + lane];
    #pragma unroll
    for (int nt = 0; nt < NT; ++nt) bh[nt] = Bsm[((wn >> 4) + nt) * 64 + lane];
    #pragma unroll
    for (int mt = 0; mt < MT; ++mt)
      #pragma unroll
      for (int nt = 0; nt < NT; ++nt)
        acc[mt][nt] = __builtin_amdgcn_mfma_f32_16x16x32_bf16(
            af[mt], bh[nt], acc[mt][nt], 0, 0, 0);
    if constexpr (SPLIT) {
      short8 bl[NT];
      #pragma unroll
      for (int nt = 0; nt < NT; ++nt) bl[nt] = Lsm[((wn >> 4) + nt) * 64 + lane];
      #pragma unroll
      for (int mt = 0; mt < MT; ++mt)
        #pragma unroll
        for (int nt = 0; nt < NT; ++nt)
          acc[mt][nt] = __builtin_amdgcn_mfma_f32_16x16x32_bf16(
              af[mt], bl[nt], acc[mt][nt], 0, 0, 0);
    }
  }
  const int col = lane & 15, qr = lane >> 4;
  #pragma unroll
  for (int mt = 0; mt < MT; ++mt) {
    int mrow = m0 + wm + mt * 16 + qr * 4;
    #pragma unroll
    for (int nt = 0; nt < NT; ++nt) {
      int nc = n0 + wn + nt * 16 + col;
      #pragma unroll
      for (int r = 0; r < 4; ++r) {
        float v = acc[mt][nt][r];
        if (MODE == 1) v = v / (1.f + __expf(-v));
        if (MODE == 3) v = tanhf(v);
        size_t oi = (size_t)(mrow + r) * N + nc;
        if (MODE == 2) ((float*)O)[oi] = v;
        else           ((bf16*)O)[oi] = f2b(v);
      }
    }
  }
}

// ---------------------------------------------------------------------------
// mix_all: one pass computes ALL FIVE mixed activations
// xf = x + (xshift-x)*(tmf + m_f),  m_f = mix5p[:, f*32:(f+1)*32] @ w2[f].
// Reads x and mix5p once (vs 5x in the per-f version). 8 rows/block, 512 thr.
// ---------------------------------------------------------------------------
__global__ __launch_bounds__(512) void mix_all_kernel(
    const bf16* __restrict__ mix5, const float* __restrict__ w2,
    const float* __restrict__ x,
    const float* __restrict__ tmw, const float* __restrict__ tmk,
    const float* __restrict__ tmv, const float* __restrict__ tmr,
    const float* __restrict__ tmg,
    bf16* __restrict__ xw, bf16* __restrict__ xk, bf16* __restrict__ xv,
    bf16* __restrict__ xr, bf16* __restrict__ xg) {
  __shared__ float M[8][160];
  int row0 = blockIdx.x * 8;
  for (int e = threadIdx.x; e < 8 * 160; e += 512) {
    int rr = e / 160, d = e - rr * 160;
    M[rr][d] = b2f(mix5[(size_t)(row0 + rr) * 192 + d]);
  }
  __syncthreads();
  int c = threadIdx.x;
  float a0[8] = {}, a1[8] = {}, a2[8] = {}, a3[8] = {}, a4[8] = {};
  for (int d = 0; d < 32; ++d) {
    float w0 = w2[(size_t)(0 * 32 + d) * C_ + c];
    float w1v= w2[(size_t)(1 * 32 + d) * C_ + c];
    float w2v= w2[(size_t)(2 * 32 + d) * C_ + c];
    float w3 = w2[(size_t)(3 * 32 + d) * C_ + c];
    float w4 = w2[(size_t)(4 * 32 + d) * C_ + c];
    #pragma unroll
    for (int r = 0; r < 8; ++r) {
      a0[r] = fmaf(M[r][d],       w0, a0[r]);
      a1[r] = fmaf(M[r][32 + d],  w1v, a1[r]);
      a2[r] = fmaf(M[r][64 + d],  w2v, a2[r]);
      a3[r] = fmaf(M[r][96 + d],  w3, a3[r]);
      a4[r] = fmaf(M[r][128 + d], w4, a4[r]);
    }
  }
  float vw = tmw[c], vk = tmk[c], vv = tmv[c], vr = tmr[c], vg = tmg[c];
  #pragma unroll
  for (int r = 0; r < 8; ++r) {
    int row = row0 + r;
    int t = row & (T_ - 1);
    size_t idx = (size_t)row * C_ + c;
    float xc = x[idx];
    float xx = ((t == 0) ? 0.f : x[idx - C_]) - xc;
    xw[idx] = f2b(xc + xx * (vw + a0[r]));
    xk[idx] = f2b(xc + xx * (vk + a1[r]));
    xv[idx] = f2b(xc + xx * (vv + a2[r]));
    xr[idx] = f2b(xc + xx * (vr + a3[r]));
    xg[idx] = f2b(xc + xx * (vg + a4[r]));
  }
}

// ---------------------------------------------------------------------------
// decay (unchanged, verified): w = td + h1 @ Wd2 (K=64); ee = exp(w) bf16.
// ---------------------------------------------------------------------------
__global__ __launch_bounds__(512) void decay_kernel(
    const bf16* __restrict__ h1, const float* __restrict__ wd2,
    const float* __restrict__ tdecay, bf16* __restrict__ ee) {
  __shared__ float Hs[8][64];
  int row0 = blockIdx.x * 8;
  {
    int e = threadIdx.x;
    Hs[e >> 6][e & 63] = b2f(h1[(size_t)(row0 + (e >> 6)) * 64 + (e & 63)]);
  }
  __syncthreads();
  int c = threadIdx.x;
  float acc[8] = {0.f,0.f,0.f,0.f,0.f,0.f,0.f,0.f};
  for (int j = 0; j < 64; ++j) {
    float wv = wd2[j * C_ + c];
    #pragma unroll
    for (int r = 0; r < 8; ++r) acc[r] += Hs[r][j] * wv;
  }
  float td = tdecay[c];
  #pragma unroll
  for (int r = 0; r < 8; ++r)
    ee[(size_t)(row0 + r) * C_ + c] = f2b(expf(td + acc[r]));
}

// ---------------------------------------------------------------------------
// WKV6 chunked scan — MFMA form (unchanged, verified round 9).
// ---------------------------------------------------------------------------
__global__ __launch_bounds__(64) void wkv_partial_mfma(
    const bf16* __restrict__ k, const bf16* __restrict__ v,
    const bf16* __restrict__ ee, float* __restrict__ st) {
  __shared__ __align__(16) char smem[17536];
  float* Lm  = (float*)smem;              // [65][32]
  bf16*  K2T = (bf16*)(smem + 8320);      // [32][72]
  bf16*  VT  = (bf16*)(smem + 12928);     // [32][72]
  int g = blockIdx.x;
  int bh = g >> 5, c = g & (NC_ - 1);
  int b = bh >> 4, h = bh & 15;
  int lane = threadIdx.x;
  size_t gbase = (size_t)b * T_ * C_ + (size_t)(c * CL_) * C_ + h * HS_;
  if (lane < 32) {
    int j = lane;
    float L = 0.f;
    for (int t = 0; t < CL_; ++t) {
      Lm[t * 32 + j] = L;
      L -= b2f(ee[gbase + (size_t)t * C_ + j]);
    }
    Lm[64 * 32 + j] = L;
  }
  __syncthreads();
  for (int it = 0; it < 32; ++it) {
    int t = it * 2 + (lane >> 5);
    int ch = lane & 31;
    size_t gi = gbase + (size_t)t * C_ + ch;
    float Lt1  = Lm[(t + 1) * 32 + ch];
    float Ltot = Lm[64 * 32 + ch];
    K2T[ch * 72 + t] = f2b(b2f(k[gi]) * __expf(Ltot - Lt1));
    VT [ch * 72 + t] = v[gi];
  }
  __syncthreads();
  const int fl = lane & 15, q = lane >> 4;
  f32x4 accS[2][2] = {};
  #pragma unroll
  for (int kc = 0; kc < 2; ++kc) {
    short8 av[2], bk[2];
    #pragma unroll
    for (int mt = 0; mt < 2; ++mt)
      av[mt] = *(const short8*)(VT + (mt * 16 + fl) * 72 + kc * 32 + q * 8);
    #pragma unroll
    for (int nt = 0; nt < 2; ++nt)
      bk[nt] = *(const short8*)(K2T + (nt * 16 + fl) * 72 + kc * 32 + q * 8);
    #pragma unroll
    for (int mt = 0; mt < 2; ++mt)
      #pragma unroll
      for (int nt = 0; nt < 2; ++nt)
        accS[mt][nt] = __builtin_amdgcn_mfma_f32_16x16x32_bf16(
            av[mt], bk[nt], accS[mt][nt], 0, 0, 0);
  }
  size_t sbase = (size_t)g * STF_;
  #pragma unroll
  for (int mt = 0; mt < 2; ++mt)
    #pragma unroll
    for (int nt = 0; nt < 2; ++nt)
      #pragma unroll
      for (int r = 0; r < 4; ++r)
        st[sbase + (size_t)(mt * 16 + q * 4 + r) * 32 + nt * 16 + fl] =
            accS[mt][nt][r];
  if (lane < 32) st[sbase + 1024 + lane] = __expf(Lm[64 * 32 + lane]);
}

__global__ __launch_bounds__(64) void wkv_stitch_kernel(float* __restrict__ st) {
  int bh = blockIdx.x;
  int lane = threadIdx.x;
  int i = lane & 31, half = lane >> 5;
  float R[16];
  #pragma unroll
  for (int jj = 0; jj < 16; ++jj) R[jj] = 0.f;
  for (int c = 0; c < NC_; ++c) {
    size_t s = ((size_t)bh * NC_ + c) * STF_;
    float* sp = st + s + i * 32 + (half << 4);
    float Sc[16];
    float4* sc4 = reinterpret_cast<float4*>(Sc);
    float4* sp4 = reinterpret_cast<float4*>(sp);
    #pragma unroll
    for (int q = 0; q < 4; ++q) sc4[q] = sp4[q];
    float Pj[16];
    #pragma unroll
    for (int jj = 0; jj < 16; ++jj) Pj[jj] = st[s + 1024 + (half << 4) + jj];
    float4* r4 = reinterpret_cast<float4*>(R);
    #pragma unroll
    for (int q = 0; q < 4; ++q) sp4[q] = r4[q];
    #pragma unroll
    for (int jj = 0; jj < 16; ++jj) R[jj] = fmaf(Pj[jj], R[jj], Sc[jj]);
  }
}

__global__ __launch_bounds__(64) void wkv_final_mfma(
    const bf16* __restrict__ r, const bf16* __restrict__ k,
    const bf16* __restrict__ v, const bf16* __restrict__ ee,
    const float* __restrict__ faaaa, const float* __restrict__ st,
    bf16* __restrict__ y) {
  __shared__ __align__(16) char smem[29440];
  float* Lm = (float*)smem;               // [65][32] — aliased by Pm later
  bf16*  Pm = (bf16*)smem;                // [64][72]
  bf16*  RA = (bf16*)(smem + 9216);       // [64][40]
  bf16*  Kd = (bf16*)(smem + 14336);      // [64][40]
  bf16*  VT = (bf16*)(smem + 19456);      // [32][72]
  bf16*  Sh = (bf16*)(smem + 24064);      // [32][40]
  bf16*  Sl = (bf16*)(smem + 26624);      // [32][40]
  float* bon = (float*)(smem + 29184);    // [64]
  int g = blockIdx.x;
  int bh = g >> 5, c = g & (NC_ - 1);
  int b = bh >> 4, h = bh & 15;
  int lane = threadIdx.x;
  size_t gbase = (size_t)b * T_ * C_ + (size_t)(c * CL_) * C_ + h * HS_;
  size_t sbase = (size_t)g * STF_;
  if (lane < 32) {
    int j = lane;
    float L = 0.f;
    for (int t = 0; t < CL_; ++t) {
      Lm[t * 32 + j] = L;
      L -= b2f(ee[gbase + (size_t)t * C_ + j]);
    }
    Lm[64 * 32 + j] = L;
  }
  for (int it = 0; it < 16; ++it) {
    int idx = it * 64 + lane;
    int i = idx >> 5, j = idx & 31;
    float s = st[sbase + idx];
    bf16 hi = f2b(s);
    Sh[i * 40 + j] = hi;
    Sl[i * 40 + j] = f2b(s - b2f(hi));
  }
  float u_j = faaaa[h * HS_ + (lane & 31)];
  __syncthreads();
  for (int it = 0; it < 32; ++it) {
    int t = it * 2 + (lane >> 5);
    int ch = lane & 31;
    size_t gi = gbase + (size_t)t * C_ + ch;
    float rv = b2f(r[gi]), kv = b2f(k[gi]);
    float Lt  = Lm[t * 32 + ch];
    float Lt1 = Lm[(t + 1) * 32 + ch];
    RA[t * 40 + ch] = f2b(rv * __expf(Lt));
    Kd[t * 40 + ch] = f2b(kv * __expf(-Lt1));
    VT[ch * 72 + t] = v[gi];
    float pb = rv * u_j * kv;
    pb += __shfl_xor(pb, 1); pb += __shfl_xor(pb, 2);
    pb += __shfl_xor(pb, 4); pb += __shfl_xor(pb, 8);
    pb += __shfl_xor(pb, 16);
    if (ch == 0) bon[t] = pb;
  }
  __syncthreads();
  const int fl = lane & 15, q = lane >> 4;
  short8 afr[4];
  #pragma unroll
  for (int mt = 0; mt < 4; ++mt)
    afr[mt] = *(const short8*)(RA + (mt * 16 + fl) * 40 + q * 8);
  f32x4 accY[4][2] = {};
  {
    short8 sh[2], sl[2];
    #pragma unroll
    for (int nt = 0; nt < 2; ++nt) {
      sh[nt] = *(const short8*)(Sh + (nt * 16 + fl) * 40 + q * 8);
      sl[nt] = *(const short8*)(Sl + (nt * 16 + fl) * 40 + q * 8);
    }
    #pragma unroll
    for (int mt = 0; mt < 4; ++mt)
      #pragma unroll
      for (int nt = 0; nt < 2; ++nt) {
        accY[mt][nt] = __builtin_amdgcn_mfma_f32_16x16x32_bf16(
            afr[mt], sh[nt], accY[mt][nt], 0, 0, 0);
        accY[mt][nt] = __builtin_amdgcn_mfma_f32_16x16x32_bf16(
            afr[mt], sl[nt], accY[mt][nt], 0, 0, 0);
      }
  }
  f32x4 accP[4][4] = {};
  {
    short8 bk[4];
    #pragma unroll
    for (int s4 = 0; s4 < 4; ++s4)
      bk[s4] = *(const short8*)(Kd + (s4 * 16 + fl) * 40 + q * 8);
    #pragma unroll
    for (int mt = 0; mt < 4; ++mt)
      #pragma unroll
      for (int s4 = 0; s4 < 4; ++s4)
        accP[mt][s4] = __builtin_amdgcn_mfma_f32_16x16x32_bf16(
            afr[mt], bk[s4], accP[mt][s4], 0, 0, 0);
  }
  __syncthreads();
  #pragma unroll
  for (int mt = 0; mt < 4; ++mt)
    #pragma unroll
    for (int s4 = 0; s4 < 4; ++s4)
      #pragma unroll
      for (int rr = 0; rr < 4; ++rr) {
        int t = mt * 16 + q * 4 + rr;
        int s = s4 * 16 + fl;
        float pv = accP[mt][s4][rr];
        float bv = bon[t];
        pv = (s < t) ? pv : ((s == t) ? bv : 0.f);
        Pm[t * 72 + s] = f2b(pv);
      }
  __syncthreads();
  {
    short8 bv[2][2];
    #pragma unroll
    for (int nt = 0; nt < 2; ++nt)
      #pragma unroll
      for (int kc = 0; kc < 2; ++kc)
        bv[nt][kc] = *(const short8*)(VT + (nt * 16 + fl) * 72 + kc * 32 + q * 8);
    #pragma unroll
    for (int mt = 0; mt < 4; ++mt)
      #pragma unroll
      for (int kc = 0; kc < 2; ++kc) {
        short8 ap = *(const short8*)(Pm + (mt * 16 + fl) * 72 + kc * 32 + q * 8);
        #pragma unroll
        for (int nt = 0; nt < 2; ++nt)
          accY[mt][nt] = __builtin_amdgcn_mfma_f32_16x16x32_bf16(
              ap, bv[nt][kc], accY[mt][nt], 0, 0, 0);
      }
  }
  #pragma unroll
  for (int mt = 0; mt < 4; ++mt)
    #pragma unroll
    for (int nt = 0; nt < 2; ++nt)
      #pragma unroll
      for (int rr = 0; rr < 4; ++rr) {
        int t = mt * 16 + q * 4 + rr;
        int i = nt * 16 + fl;
        y[gbase + (size_t)t * C_ + i] = f2b(accY[mt][nt][rr]);
      }
}

// ---------------------------------------------------------------------------
// groupnorm over HS=32, * ln_w + ln_b, * silu(g) -> z bf16  (unchanged)
// ---------------------------------------------------------------------------
__global__ __launch_bounds__(256) void gnorm_kernel(
    const bf16* __restrict__ y, const bf16* __restrict__ g,
    const float* __restrict__ lnw, const float* __restrict__ lnb,
    bf16* __restrict__ z) {
  int grp = blockIdx.x * 8 + (threadIdx.x >> 5);
  int i = threadIdx.x & 31;
  int token = grp >> 4, h = grp & 15;
  size_t idx = (size_t)token * C_ + h * HS_ + i;
  float yv = b2f(y[idx]);
  float mu = yv;
  mu += __shfl_xor(mu, 1); mu += __shfl_xor(mu, 2); mu += __shfl_xor(mu, 4);
  mu += __shfl_xor(mu, 8); mu += __shfl_xor(mu, 16);
  mu *= (1.f / 32.f);
  float d = yv - mu;
  float var = d * d;
  var += __shfl_xor(var, 1); var += __shfl_xor(var, 2); var += __shfl_xor(var, 4);
  var += __shfl_xor(var, 8); var += __shfl_xor(var, 16);
  var *= (1.f / 32.f);
  float yn = d * rsqrtf(var + 1e-5f);
  int c = h * HS_ + i;
  float outv = (yn * lnw[c] + lnb[c]) * b2f(g[idx]);
  z[idx] = f2b(outv);
}

// ---------------------------------------------------------------------------
extern "C" void kernel_launch(void* const* d_in, const int* in_sizes, int n_in,
                              void* d_out, int out_size, void* d_ws, size_t ws_size,
                              hipStream_t stream) {
  (void)in_sizes; (void)n_in; (void)out_size; (void)ws_size;
  const float* x      = (const float*)d_in[0];
  const float* tmx    = (const float*)d_in[1];
  const float* tmw    = (const float*)d_in[2];
  const float* tmk    = (const float*)d_in[3];
  const float* tmv    = (const float*)d_in[4];
  const float* tmr    = (const float*)d_in[5];
  const float* tmg    = (const float*)d_in[6];
  const float* w1     = (const float*)d_in[7];
  const float* w2     = (const float*)d_in[8];
  const float* tdecay = (const float*)d_in[9];
  const float* wd1    = (const float*)d_in[10];
  const float* wd2    = (const float*)d_in[11];
  const float* faaaa  = (const float*)d_in[12];
  const float* Wr     = (const float*)d_in[13];
  const float* Wk     = (const float*)d_in[14];
  const float* Wv     = (const float*)d_in[15];
  const float* Wg     = (const float*)d_in[16];
  const float* Wo     = (const float*)d_in[17];
  const float* lnw    = (const float*)d_in[18];
  const float* lnb    = (const float*)d_in[19];
  float* out = (float*)d_out;

  // workspace layout — 6 x 16MB slots + st + weights; peak 117.75 MB
  // (<= 119.25 MB proven safe in rounds 3/4 A-B)
  char* w8 = (char*)d_ws;
  const size_t MB = 1024ull * 1024ull;
  bf16* S0 = (bf16*)(w8 +  0 * MB);  // xxx -> xw -> ee
  bf16* S1 = (bf16*)(w8 + 16 * MB);  // xk -> vb
  bf16* S2 = (bf16*)(w8 + 32 * MB);  // xv -> gb
  bf16* S3 = (bf16*)(w8 + 48 * MB);  // xr -> kb -> zb
  bf16* S4 = (bf16*)(w8 + 64 * MB);  // xg -> y
  bf16* S5 = (bf16*)(w8 + 80 * MB);  // mix5p+h1 -> rb
  float* st = (float*)(w8 + 96 * MB);            // 16.5 MB
  char* wreg = w8 + 112 * MB + 512 * 1024;       // weights at 112.5 MB
  bf16* Wrb  = (bf16*)(wreg);
  bf16* Wkb  = Wrb + 2 * WSZ_;
  bf16* Wvb  = Wkb + 2 * WSZ_;
  bf16* Wgb  = Wvb + 2 * WSZ_;
  bf16* Wob  = Wgb + 2 * WSZ_;
  bf16* w1p  = Wob + 2 * WSZ_;                   // [192][512]
  bf16* wd1p = w1p + 192 * 512;                  // [64][512]
  bf16* mix5p = S5;                              // [16384][192], 6 MB
  bf16* h1    = S5 + (size_t)BT_ * 192;          // [16384][64],  2 MB

  // 1. fused prep: xxx (S0) + weight splits + w1/wd1 transpose
  prep_combo_kernel<<<PREP_N_, 256, 0, stream>>>(
      x, tmx, Wr, Wk, Wv, Wg, Wo, w1, wd1,
      S0, Wrb, Wkb, Wvb, Wgb, Wob, w1p, wd1p);
  // 2. mix5p = tanh(xxx @ w1p^T)
  mfma_gemm_kernel<64, 3, 0><<<dim3(128, 3), 256, 0, stream>>>(S0, w1p, mix5p, 192);
  // 3. all five mixed activations in one pass (xxx dead -> xw overwrites S0)
  mix_all_kernel<<<BT_ / 8, 512, 0, stream>>>(mix5p, w2, x,
      tmw, tmk, tmv, tmr, tmg, S0, S1, S2, S3, S4);
  // 4. h1 = tanh(xw @ wd1^T);  5. ee = exp(td + h1 @ wd2)  (ee over xw slot)
  mfma_gemm_kernel<64, 3, 0><<<dim3(128, 1), 256, 0, stream>>>(S0, wd1p, h1, 64);
  decay_kernel<<<BT_ / 8, 512, 0, stream>>>(h1, wd2, tdecay, S0);
  // 6-9. projections (split weights): r->S5, k->S3's... k->S3? no: see map
  dim3 gg(128, 4);
  mfma_gemm_kernel<128, 0, 1><<<gg, 256, 0, stream>>>(S3, Wrb, S5, C_);  // xr->rb(S5)
  mfma_gemm_kernel<128, 0, 1><<<gg, 256, 0, stream>>>(S1, Wkb, S3, C_);  // xk->kb(S3)
  mfma_gemm_kernel<128, 0, 1><<<gg, 256, 0, stream>>>(S2, Wvb, S1, C_);  // xv->vb(S1)
  mfma_gemm_kernel<128, 1, 1><<<gg, 256, 0, stream>>>(S4, Wgb, S2, C_);  // xg->gb(S2), silu
  // 10-12. chunk-parallel WKV6 scan (MFMA form)
  wkv_partial_mfma<<<B_ * H_ * NC_, 64, 0, stream>>>(S3, S1, S0, st);
  wkv_stitch_kernel<<<B_ * H_, 64, 0, stream>>>(st);
  wkv_final_mfma<<<B_ * H_ * NC_, 64, 0, stream>>>(S5, S3, S1, S0, faaaa, st, S4);
  // 13. groupnorm * g -> zb (S3; kb dead)   14. output projection (fp32)
  gnorm_kernel<<<(BT_ * H_) / 8, 256, 0, stream>>>(S4, S2, lnw, lnb, S3);
  mfma_gemm_kernel<128, 2, 1><<<gg, 256, 0, stream>>>(S3, Wob, out, C_);
}